// Round 4
// baseline (443.656 us; speedup 1.0000x reference)
//
#include <hip/hip_runtime.h>

// HamiltonianMetric: y[b] = u^T u, u = scatter(tanh(MLP(x))).
// R4: fix R3's stage-3 register defeat (VGPR=60 proved spill/sink of the
// prefetch arrays). Stage 3 now uses fully-NAMED registers with an explicit
// software pipeline (issue tile t+1 -> compute tile t -> rename). Split kept:
// K1 MLP writes padded-triangle u into out regions; K2 Gram at HBM roofline.

typedef __bf16 bf16_t;
typedef bf16_t bf16x8 __attribute__((ext_vector_type(8)));
typedef float  f32x4  __attribute__((ext_vector_type(4)));

#define MFMA16(a, b, c) __builtin_amdgcn_mfma_f32_16x16x32_bf16((a), (b), (c), 0, 0, 0)

constexpr int SLOT = 4624;  // LDS slot stride (4608 data + 16 pad)
constexpr int USZ  = 4608;  // bytes of padded triangle per batch

__device__ __forceinline__ float fast_tanh(float x) {
  float cx = fminf(fmaxf(x, -30.0f), 30.0f);
  float t  = __expf(2.0f * cx);
  return (t - 1.0f) * __builtin_amdgcn_rcpf(t + 1.0f);
}

__device__ __forceinline__ bf16x8 zsel(bf16x8 f, bool keep) {
  union { bf16x8 v; unsigned int u[4]; } x;
  x.v = f;
  unsigned m = keep ? 0xFFFFFFFFu : 0u;
#pragma unroll
  for (int p = 0; p < 4; ++p) x.u[p] &= m;
  return x.v;
}

// padded position p -> (j, k): row j has j+1 valid entries, padded to 8-mult
__device__ __forceinline__ void decode_p(int p, int& j, int& k) {
  int cc = p >> 3, e = p & 7;
  int b = 0;
  while (b < 7 && cc >= 4 * (b + 1) * (b + 2)) ++b;
  int rl  = b + 1;
  int rem = cc - 4 * b * (b + 1);
  j = 8 * b + rem / rl;
  k = (rem % rl) * 8 + e;
}

// ws: [0,16384) W1t[256][64] | [16384,81920) W2t[256][256] |
//     [81920,671744) W3p[2304][256] | byte 1343488: b3p[2304] f32
__global__ void prep_kernel(const float* __restrict__ W1, const float* __restrict__ W2,
                            const float* __restrict__ W3, const float* __restrict__ b3,
                            char* __restrict__ wsb) {
  int tid = blockIdx.x * 512 + threadIdx.x;
  bf16_t* ws = (bf16_t*)wsb;
  if (tid < 16384) {
    int n = tid >> 6, k = tid & 63;
    ws[tid] = (bf16_t)W1[k * 256 + n];
  } else if (tid < 81920) {
    int m = tid - 16384;
    int n = m >> 8, k = m & 255;
    ws[tid] = (bf16_t)W2[k * 256 + n];
  } else if (tid < 671744) {
    int m = tid - 81920;
    int p = m >> 8, kcol = m & 255;
    int j, k;
    decode_p(p, j, k);
    float v = 0.f;
    if (k <= j) {
      int n_ref = (k == j) ? j : (64 + k * 63 - (k * (k - 1)) / 2 + j - k - 1);
      v = W3[kcol * 2080 + n_ref];
    }
    ws[tid] = (bf16_t)v;
  } else if (tid < 674048) {
    int p = tid - 671744;
    int j, k;
    decode_p(p, j, k);
    float v = 0.f;
    if (k <= j) {
      int n_ref = (k == j) ? j : (64 + k * 63 - (k * (k - 1)) / 2 + j - k - 1);
      v = b3[n_ref];
    }
    ((float*)(wsb + 1343488))[p] = v;
  }
}

// ---------------- kernel 1: MLP, 16 batches/block ----------------
__global__ void __launch_bounds__(512, 4)
hm_mlp_kernel(const float* __restrict__ x, const float* __restrict__ b1,
              const float* __restrict__ b2, const char* __restrict__ wsb,
              float* __restrict__ out) {
  extern __shared__ char smem[];  // 73984 B: 16 uT slots
  const int tid  = threadIdx.x;
  const int w    = tid >> 6;
  const int lane = tid & 63;
  const int g    = lane >> 4;
  const int c    = lane & 15;
  const int blk  = blockIdx.x;

  const bf16_t* W1t = (const bf16_t*)wsb;
  const bf16_t* W2t = W1t + 16384;
  const bf16_t* W3p = W1t + 81920;
  const float*  b3p = (const float*)(wsb + 1343488);

  char* xs  = smem;          // [16][64]  bf16, swz
  char* h1s = smem + 4096;   // [16][256] bf16, swz
  char* h2s = smem + 16384;  // [16][256] bf16, swz

  if (tid < 256) {
    f32x4 v = *(const f32x4*)(x + (size_t)blk * 1024 + tid * 4);
    int row = tid >> 4, col = (tid & 15) * 4;
    union { bf16_t b[4]; unsigned long long u; } pk;
    pk.b[0] = (bf16_t)v[0]; pk.b[1] = (bf16_t)v[1];
    pk.b[2] = (bf16_t)v[2]; pk.b[3] = (bf16_t)v[3];
    *(unsigned long long*)(xs + ((row * 128 + col * 2) ^ ((row & 7) << 4))) = pk.u;
  }
  __syncthreads();

  // stage 1
  {
    bf16x8 a0 = *(const bf16x8*)(xs + ((c * 128 + g * 16) ^ ((c & 7) << 4)));
    bf16x8 a1 = *(const bf16x8*)(xs + ((c * 128 + 64 + g * 16) ^ ((c & 7) << 4)));
#pragma unroll
    for (int ni = 0; ni < 2; ++ni) {
      int n = (w * 2 + ni) * 16 + c;
      bf16x8 bw0 = *(const bf16x8*)(W1t + n * 64 + g * 8);
      bf16x8 bw1 = *(const bf16x8*)(W1t + n * 64 + 32 + g * 8);
      f32x4 acc = {0.f, 0.f, 0.f, 0.f};
      acc = MFMA16(a0, bw0, acc);
      acc = MFMA16(a1, bw1, acc);
      float bias = b1[n];
#pragma unroll
      for (int r = 0; r < 4; ++r) {
        int row = g * 4 + r;
        float v = fast_tanh(acc[r] + bias);
        *(bf16_t*)(h1s + ((row * 512 + n * 2) ^ ((row & 7) << 4))) = (bf16_t)v;
      }
    }
  }
  __syncthreads();

  // stage 2
#pragma unroll
  for (int ni = 0; ni < 2; ++ni) {
    int n = (w * 2 + ni) * 16 + c;
    f32x4 acc0 = {0.f, 0.f, 0.f, 0.f}, acc1 = {0.f, 0.f, 0.f, 0.f};
#pragma unroll
    for (int kk = 0; kk < 8; kk += 2) {
      bf16x8 a0 = *(const bf16x8*)(h1s + ((c * 512 + kk * 64 + g * 16) ^ ((c & 7) << 4)));
      bf16x8 a1 = *(const bf16x8*)(h1s + ((c * 512 + (kk + 1) * 64 + g * 16) ^ ((c & 7) << 4)));
      bf16x8 bw0 = *(const bf16x8*)(W2t + n * 256 + kk * 32 + g * 8);
      bf16x8 bw1 = *(const bf16x8*)(W2t + n * 256 + (kk + 1) * 32 + g * 8);
      acc0 = MFMA16(a0, bw0, acc0);
      acc1 = MFMA16(a1, bw1, acc1);
    }
    f32x4 acc = acc0 + acc1;
    float bias = b2[n];
#pragma unroll
    for (int r = 0; r < 4; ++r) {
      int row = g * 4 + r;
      float v = fast_tanh(acc[r] + bias);
      *(bf16_t*)(h2s + ((row * 512 + n * 2) ^ ((row & 7) << 4))) = (bf16_t)v;
    }
  }
  __syncthreads();

  // ---- stage 3: named-register software pipeline, 18 tiles/wave ----
  {
    // A-fragments of h2 (this wave's 16 batches), named regs
    bf16x8 a0 = *(const bf16x8*)(h2s + ((c * 512 + 0 * 64 + g * 16) ^ ((c & 7) << 4)));
    bf16x8 a1 = *(const bf16x8*)(h2s + ((c * 512 + 1 * 64 + g * 16) ^ ((c & 7) << 4)));
    bf16x8 a2 = *(const bf16x8*)(h2s + ((c * 512 + 2 * 64 + g * 16) ^ ((c & 7) << 4)));
    bf16x8 a3 = *(const bf16x8*)(h2s + ((c * 512 + 3 * 64 + g * 16) ^ ((c & 7) << 4)));
    bf16x8 a4 = *(const bf16x8*)(h2s + ((c * 512 + 4 * 64 + g * 16) ^ ((c & 7) << 4)));
    bf16x8 a5 = *(const bf16x8*)(h2s + ((c * 512 + 5 * 64 + g * 16) ^ ((c & 7) << 4)));
    bf16x8 a6 = *(const bf16x8*)(h2s + ((c * 512 + 6 * 64 + g * 16) ^ ((c & 7) << 4)));
    bf16x8 a7 = *(const bf16x8*)(h2s + ((c * 512 + 7 * 64 + g * 16) ^ ((c & 7) << 4)));
    __syncthreads();  // arena now free: 16 uT slots

    int p0 = (w * 16 + c);
    const bf16_t* bp = W3p + p0 * 256 + g * 8;
    bf16x8 c0 = *(const bf16x8*)(bp + 0);
    bf16x8 c1 = *(const bf16x8*)(bp + 32);
    bf16x8 c2 = *(const bf16x8*)(bp + 64);
    bf16x8 c3 = *(const bf16x8*)(bp + 96);
    bf16x8 c4 = *(const bf16x8*)(bp + 128);
    bf16x8 c5 = *(const bf16x8*)(bp + 160);
    bf16x8 c6 = *(const bf16x8*)(bp + 192);
    bf16x8 c7 = *(const bf16x8*)(bp + 224);
    float  cb = b3p[p0];
    char*  tw = smem + (g * 4) * SLOT;

#pragma unroll 1
    for (int it = 0; it < 18; ++it) {
      // issue next tile's loads first (named regs -> un-spillable pipeline)
      int itn = (it < 17) ? (it + 1) : 17;  // last iter: redundant reload
      int pn  = (w + itn * 8) * 16 + c;
      const bf16_t* np = W3p + pn * 256 + g * 8;
      bf16x8 n0 = *(const bf16x8*)(np + 0);
      bf16x8 n1 = *(const bf16x8*)(np + 32);
      bf16x8 n2 = *(const bf16x8*)(np + 64);
      bf16x8 n3 = *(const bf16x8*)(np + 96);
      bf16x8 n4 = *(const bf16x8*)(np + 128);
      bf16x8 n5 = *(const bf16x8*)(np + 160);
      bf16x8 n6 = *(const bf16x8*)(np + 192);
      bf16x8 n7 = *(const bf16x8*)(np + 224);
      float  nb = b3p[pn];

      // compute current tile
      f32x4 acc0 = {0.f, 0.f, 0.f, 0.f}, acc1 = {0.f, 0.f, 0.f, 0.f};
      acc0 = MFMA16(a0, c0, acc0); acc1 = MFMA16(a1, c1, acc1);
      acc0 = MFMA16(a2, c2, acc0); acc1 = MFMA16(a3, c3, acc1);
      acc0 = MFMA16(a4, c4, acc0); acc1 = MFMA16(a5, c5, acc1);
      acc0 = MFMA16(a6, c6, acc0); acc1 = MFMA16(a7, c7, acc1);
      f32x4 acc = acc0 + acc1;

      int p = (w + it * 8) * 16 + c;
#pragma unroll
      for (int r = 0; r < 4; ++r) {
        float v = fast_tanh(acc[r] + cb);
        *(bf16_t*)(tw + r * SLOT + p * 2) = (bf16_t)v;
      }

      // rotate pipeline registers
      c0 = n0; c1 = n1; c2 = n2; c3 = n3;
      c4 = n4; c5 = n5; c6 = n6; c7 = n7; cb = nb;
    }
  }
  __syncthreads();

  // copy-out: slot m -> first 4608 B of batch (blk*16+m)'s output region
#pragma unroll
  for (int m2 = 0; m2 < 2; ++m2) {
    int m = w * 2 + m2;
    const char* s = smem + m * SLOT;
    char* dst = (char*)out + (size_t)(blk * 16 + m) * 16384;
#pragma unroll
    for (int i = 0; i < 5; ++i) {
      int off = i * 1024 + lane * 16;
      if (off < USZ) *(f32x4*)(dst + off) = *(const f32x4*)(s + off);
    }
  }
}

// ---------------- kernel 2: Gram, 1 batch per wave, no barriers ----------------
__global__ void __launch_bounds__(256, 4)
hm_gram_kernel(float* __restrict__ out) {
  extern __shared__ char smem[];  // 4 waves x 4096 B y-staging
  const int tid  = threadIdx.x;
  const int w    = tid >> 6;
  const int lane = tid & 63;
  const int g    = lane >> 4;
  const int c    = lane & 15;

  size_t batch = (size_t)blockIdx.x * 4 + w;
  const char* ub = (const char*)out + batch * 16384;  // padded-triangle u
  char* ys = smem + w * 4096;

  // direct global frag loads (each u element read exactly once)
  bf16x8 f0, f1, f2, f3, f2b, f3b;
#pragma unroll
  for (int ti = 0; ti < 4; ++ti) {
    int j = ti * 16 + c;
    int Q = j >> 3, s = j & 7;
    int ro = 16 * (4 * Q * (Q + 1) + s * (Q + 1));
    bf16x8 fa = *(const bf16x8*)(ub + ro + g * 16);
    if (ti == 0) f0 = zsel(fa, g * 8 <= j);
    if (ti == 1) f1 = zsel(fa, g * 8 <= j);
    if (ti == 2) f2 = fa;
    if (ti == 3) f3 = fa;
    if (ti >= 2) {
      bf16x8 fb = *(const bf16x8*)(ub + ro + 64 + g * 16);
      fb = zsel(fb, 32 + g * 8 <= j);
      if (ti == 2) f2b = fb;
      else         f3b = fb;
    }
  }

  bf16x8 fA[4] = {f0, f1, f2, f3};
  f32x4 acc[4][4];
#pragma unroll
  for (int ti = 0; ti < 4; ++ti)
#pragma unroll
    for (int tj = 0; tj < 4; ++tj) {
      f32x4 z = {0.f, 0.f, 0.f, 0.f};
      acc[ti][tj] = MFMA16(fA[ti], fA[tj], z);
    }
  acc[2][2] = MFMA16(f2b, f2b, acc[2][2]);
  acc[2][3] = MFMA16(f2b, f3b, acc[2][3]);
  acc[3][2] = MFMA16(f3b, f2b, acc[3][2]);
  acc[3][3] = MFMA16(f3b, f3b, acc[3][3]);

  // y write: stage 4KB (one ti-stripe) in LDS, store 1KB-contiguous dwordx4
  char* yb = (char*)out + batch * 16384;
#pragma unroll
  for (int ti = 0; ti < 4; ++ti) {
#pragma unroll
    for (int tj = 0; tj < 4; ++tj)
#pragma unroll
      for (int r = 0; r < 4; ++r)
        *(float*)(ys + (g * 4 + r) * 256 + (tj * 16 + c) * 4) = acc[ti][tj][r];
#pragma unroll
    for (int ii = 0; ii < 4; ++ii) {
      f32x4 v = *(const f32x4*)(ys + ii * 1024 + lane * 16);
      *(f32x4*)(yb + ti * 4096 + ii * 1024 + lane * 16) = v;
    }
  }
}

extern "C" void kernel_launch(void* const* d_in, const int* in_sizes, int n_in,
                              void* d_out, int out_size, void* d_ws, size_t ws_size,
                              hipStream_t stream) {
  (void)in_sizes; (void)n_in; (void)out_size; (void)ws_size;
  const float* x  = (const float*)d_in[0];
  const float* W1 = (const float*)d_in[1];
  const float* b1 = (const float*)d_in[2];
  const float* W2 = (const float*)d_in[3];
  const float* b2 = (const float*)d_in[4];
  const float* W3 = (const float*)d_in[5];
  const float* b3 = (const float*)d_in[6];
  char* wsb = (char*)d_ws;   // needs 1,352,704 B
  float* out = (float*)d_out;

  prep_kernel<<<1317, 512, 0, stream>>>(W1, W2, W3, b3, wsb);

  hipFuncSetAttribute((const void*)hm_mlp_kernel,
                      hipFuncAttributeMaxDynamicSharedMemorySize, 73984);
  hm_mlp_kernel<<<2048, 512, 73984, stream>>>(x, b1, b2, wsb, out);

  hm_gram_kernel<<<8192, 256, 16384, stream>>>(out);
}

// Round 5
// 443.078 us; speedup vs baseline: 1.0013x; 1.0013x over previous
//
#include <hip/hip_runtime.h>

// HamiltonianMetric: y[b] = u^T u, u = scatter(tanh(MLP(x))).
// R5: anchor stage-3's software pipeline with asm-volatile register pins
// (R3/R4 proved the compiler sinks prefetch loads to use -> serial L2-latency
// stalls; VGPR 60/44 was the tell). Loads now issue grouped, overlap compute,
// single vmcnt wait per tile. Split kept: K2 Gram is at HBM roofline.

typedef __bf16 bf16_t;
typedef bf16_t bf16x8 __attribute__((ext_vector_type(8)));
typedef float  f32x4  __attribute__((ext_vector_type(4)));

#define MFMA16(a, b, c) __builtin_amdgcn_mfma_f32_16x16x32_bf16((a), (b), (c), 0, 0, 0)

constexpr int SLOT = 4624;  // LDS slot stride (4608 data + 16 pad)
constexpr int USZ  = 4608;  // bytes of padded triangle per batch

__device__ __forceinline__ float fast_tanh(float x) {
  float cx = fminf(fmaxf(x, -30.0f), 30.0f);
  float t  = __expf(2.0f * cx);
  return (t - 1.0f) * __builtin_amdgcn_rcpf(t + 1.0f);
}

__device__ __forceinline__ bf16x8 zsel(bf16x8 f, bool keep) {
  union { bf16x8 v; unsigned int u[4]; } x;
  x.v = f;
  unsigned m = keep ? 0xFFFFFFFFu : 0u;
#pragma unroll
  for (int p = 0; p < 4; ++p) x.u[p] &= m;
  return x.v;
}

// padded position p -> (j, k): row j has j+1 valid entries, padded to 8-mult
__device__ __forceinline__ void decode_p(int p, int& j, int& k) {
  int cc = p >> 3, e = p & 7;
  int b = 0;
  while (b < 7 && cc >= 4 * (b + 1) * (b + 2)) ++b;
  int rl  = b + 1;
  int rem = cc - 4 * b * (b + 1);
  j = 8 * b + rem / rl;
  k = (rem % rl) * 8 + e;
}

// ws: [0,16384) W1t[256][64] | [16384,81920) W2t[256][256] |
//     [81920,671744) W3p[2304][256] | byte 1343488: b3p[2304] f32
__global__ void prep_kernel(const float* __restrict__ W1, const float* __restrict__ W2,
                            const float* __restrict__ W3, const float* __restrict__ b3,
                            char* __restrict__ wsb) {
  int tid = blockIdx.x * 512 + threadIdx.x;
  bf16_t* ws = (bf16_t*)wsb;
  if (tid < 16384) {
    int n = tid >> 6, k = tid & 63;
    ws[tid] = (bf16_t)W1[k * 256 + n];
  } else if (tid < 81920) {
    int m = tid - 16384;
    int n = m >> 8, k = m & 255;
    ws[tid] = (bf16_t)W2[k * 256 + n];
  } else if (tid < 671744) {
    int m = tid - 81920;
    int p = m >> 8, kcol = m & 255;
    int j, k;
    decode_p(p, j, k);
    float v = 0.f;
    if (k <= j) {
      int n_ref = (k == j) ? j : (64 + k * 63 - (k * (k - 1)) / 2 + j - k - 1);
      v = W3[kcol * 2080 + n_ref];
    }
    ws[tid] = (bf16_t)v;
  } else if (tid < 674048) {
    int p = tid - 671744;
    int j, k;
    decode_p(p, j, k);
    float v = 0.f;
    if (k <= j) {
      int n_ref = (k == j) ? j : (64 + k * 63 - (k * (k - 1)) / 2 + j - k - 1);
      v = b3[n_ref];
    }
    ((float*)(wsb + 1343488))[p] = v;
  }
}

// ---------------- kernel 1: MLP, 16 batches/block ----------------
__global__ void __launch_bounds__(512, 4)
hm_mlp_kernel(const float* __restrict__ x, const float* __restrict__ b1,
              const float* __restrict__ b2, const char* __restrict__ wsb,
              float* __restrict__ out) {
  extern __shared__ char smem[];  // 73984 B: 16 uT slots
  const int tid  = threadIdx.x;
  const int w    = tid >> 6;
  const int lane = tid & 63;
  const int g    = lane >> 4;
  const int c    = lane & 15;
  const int blk  = blockIdx.x;

  const bf16_t* W1t = (const bf16_t*)wsb;
  const bf16_t* W2t = W1t + 16384;
  const bf16_t* W3p = W1t + 81920;
  const float*  b3p = (const float*)(wsb + 1343488);

  char* xs  = smem;          // [16][64]  bf16, swz
  char* h1s = smem + 4096;   // [16][256] bf16, swz
  char* h2s = smem + 16384;  // [16][256] bf16, swz

  if (tid < 256) {
    f32x4 v = *(const f32x4*)(x + (size_t)blk * 1024 + tid * 4);
    int row = tid >> 4, col = (tid & 15) * 4;
    union { bf16_t b[4]; unsigned long long u; } pk;
    pk.b[0] = (bf16_t)v[0]; pk.b[1] = (bf16_t)v[1];
    pk.b[2] = (bf16_t)v[2]; pk.b[3] = (bf16_t)v[3];
    *(unsigned long long*)(xs + ((row * 128 + col * 2) ^ ((row & 7) << 4))) = pk.u;
  }
  __syncthreads();

  // stage 1
  {
    bf16x8 a0 = *(const bf16x8*)(xs + ((c * 128 + g * 16) ^ ((c & 7) << 4)));
    bf16x8 a1 = *(const bf16x8*)(xs + ((c * 128 + 64 + g * 16) ^ ((c & 7) << 4)));
#pragma unroll
    for (int ni = 0; ni < 2; ++ni) {
      int n = (w * 2 + ni) * 16 + c;
      bf16x8 bw0 = *(const bf16x8*)(W1t + n * 64 + g * 8);
      bf16x8 bw1 = *(const bf16x8*)(W1t + n * 64 + 32 + g * 8);
      f32x4 acc = {0.f, 0.f, 0.f, 0.f};
      acc = MFMA16(a0, bw0, acc);
      acc = MFMA16(a1, bw1, acc);
      float bias = b1[n];
#pragma unroll
      for (int r = 0; r < 4; ++r) {
        int row = g * 4 + r;
        float v = fast_tanh(acc[r] + bias);
        *(bf16_t*)(h1s + ((row * 512 + n * 2) ^ ((row & 7) << 4))) = (bf16_t)v;
      }
    }
  }
  __syncthreads();

  // stage 2
#pragma unroll
  for (int ni = 0; ni < 2; ++ni) {
    int n = (w * 2 + ni) * 16 + c;
    f32x4 acc0 = {0.f, 0.f, 0.f, 0.f}, acc1 = {0.f, 0.f, 0.f, 0.f};
#pragma unroll
    for (int kk = 0; kk < 8; kk += 2) {
      bf16x8 a0 = *(const bf16x8*)(h1s + ((c * 512 + kk * 64 + g * 16) ^ ((c & 7) << 4)));
      bf16x8 a1 = *(const bf16x8*)(h1s + ((c * 512 + (kk + 1) * 64 + g * 16) ^ ((c & 7) << 4)));
      bf16x8 bw0 = *(const bf16x8*)(W2t + n * 256 + kk * 32 + g * 8);
      bf16x8 bw1 = *(const bf16x8*)(W2t + n * 256 + (kk + 1) * 32 + g * 8);
      acc0 = MFMA16(a0, bw0, acc0);
      acc1 = MFMA16(a1, bw1, acc1);
    }
    f32x4 acc = acc0 + acc1;
    float bias = b2[n];
#pragma unroll
    for (int r = 0; r < 4; ++r) {
      int row = g * 4 + r;
      float v = fast_tanh(acc[r] + bias);
      *(bf16_t*)(h2s + ((row * 512 + n * 2) ^ ((row & 7) << 4))) = (bf16_t)v;
    }
  }
  __syncthreads();

  // ---- stage 3: named-register software pipeline, asm-anchored ----
  {
    bf16x8 a0 = *(const bf16x8*)(h2s + ((c * 512 + 0 * 64 + g * 16) ^ ((c & 7) << 4)));
    bf16x8 a1 = *(const bf16x8*)(h2s + ((c * 512 + 1 * 64 + g * 16) ^ ((c & 7) << 4)));
    bf16x8 a2 = *(const bf16x8*)(h2s + ((c * 512 + 2 * 64 + g * 16) ^ ((c & 7) << 4)));
    bf16x8 a3 = *(const bf16x8*)(h2s + ((c * 512 + 3 * 64 + g * 16) ^ ((c & 7) << 4)));
    bf16x8 a4 = *(const bf16x8*)(h2s + ((c * 512 + 4 * 64 + g * 16) ^ ((c & 7) << 4)));
    bf16x8 a5 = *(const bf16x8*)(h2s + ((c * 512 + 5 * 64 + g * 16) ^ ((c & 7) << 4)));
    bf16x8 a6 = *(const bf16x8*)(h2s + ((c * 512 + 6 * 64 + g * 16) ^ ((c & 7) << 4)));
    bf16x8 a7 = *(const bf16x8*)(h2s + ((c * 512 + 7 * 64 + g * 16) ^ ((c & 7) << 4)));
    __syncthreads();  // arena now free: 16 uT slots

    int p0 = (w * 16 + c);
    const bf16_t* bp = W3p + p0 * 256 + g * 8;
    bf16x8 c0 = *(const bf16x8*)(bp + 0);
    bf16x8 c1 = *(const bf16x8*)(bp + 32);
    bf16x8 c2 = *(const bf16x8*)(bp + 64);
    bf16x8 c3 = *(const bf16x8*)(bp + 96);
    bf16x8 c4 = *(const bf16x8*)(bp + 128);
    bf16x8 c5 = *(const bf16x8*)(bp + 160);
    bf16x8 c6 = *(const bf16x8*)(bp + 192);
    bf16x8 c7 = *(const bf16x8*)(bp + 224);
    float  cb = b3p[p0];
    // anchor: loads above must complete here, can't sink into the loop
    asm volatile("" :: "v"(c0), "v"(c1), "v"(c2), "v"(c3),
                       "v"(c4), "v"(c5), "v"(c6), "v"(c7));
    char* tw = smem + (g * 4) * SLOT;

#pragma unroll 1
    for (int it = 0; it < 18; ++it) {
      // issue next tile's loads (grouped, overlap current tile's compute)
      int itn = (it < 17) ? (it + 1) : 17;  // last iter: redundant reload
      int pn  = (w + itn * 8) * 16 + c;
      const bf16_t* np = W3p + pn * 256 + g * 8;
      bf16x8 n0 = *(const bf16x8*)(np + 0);
      bf16x8 n1 = *(const bf16x8*)(np + 32);
      bf16x8 n2 = *(const bf16x8*)(np + 64);
      bf16x8 n3 = *(const bf16x8*)(np + 96);
      bf16x8 n4 = *(const bf16x8*)(np + 128);
      bf16x8 n5 = *(const bf16x8*)(np + 160);
      bf16x8 n6 = *(const bf16x8*)(np + 192);
      bf16x8 n7 = *(const bf16x8*)(np + 224);
      float  nb = b3p[pn];

      // compute current tile (c regs) while n-loads are in flight
      f32x4 acc0 = {0.f, 0.f, 0.f, 0.f}, acc1 = {0.f, 0.f, 0.f, 0.f};
      acc0 = MFMA16(a0, c0, acc0); acc1 = MFMA16(a1, c1, acc1);
      acc0 = MFMA16(a2, c2, acc0); acc1 = MFMA16(a3, c3, acc1);
      acc0 = MFMA16(a4, c4, acc0); acc1 = MFMA16(a5, c5, acc1);
      acc0 = MFMA16(a6, c6, acc0); acc1 = MFMA16(a7, c7, acc1);
      f32x4 acc = acc0 + acc1;

      int p = (w + it * 8) * 16 + c;
#pragma unroll
      for (int r = 0; r < 4; ++r) {
        float v = fast_tanh(acc[r] + cb);
        *(bf16_t*)(tw + r * SLOT + p * 2) = (bf16_t)v;
      }

      // anchor: n-loads cannot sink past this point (they are "used" here),
      // so the group-wait lands AFTER the compute above, not inside it.
      asm volatile("" :: "v"(n0), "v"(n1), "v"(n2), "v"(n3),
                         "v"(n4), "v"(n5), "v"(n6), "v"(n7), "v"(nb));

      // rotate pipeline registers
      c0 = n0; c1 = n1; c2 = n2; c3 = n3;
      c4 = n4; c5 = n5; c6 = n6; c7 = n7; cb = nb;
    }
  }
  __syncthreads();

  // copy-out: slot m -> first 4608 B of batch (blk*16+m)'s output region
#pragma unroll
  for (int m2 = 0; m2 < 2; ++m2) {
    int m = w * 2 + m2;
    const char* s = smem + m * SLOT;
    char* dst = (char*)out + (size_t)(blk * 16 + m) * 16384;
#pragma unroll
    for (int i = 0; i < 5; ++i) {
      int off = i * 1024 + lane * 16;
      if (off < USZ) *(f32x4*)(dst + off) = *(const f32x4*)(s + off);
    }
  }
}

// ---------------- kernel 2: Gram, 1 batch per wave, no barriers ----------------
__global__ void __launch_bounds__(256, 4)
hm_gram_kernel(float* __restrict__ out) {
  extern __shared__ char smem[];  // 4 waves x 4096 B y-staging
  const int tid  = threadIdx.x;
  const int w    = tid >> 6;
  const int lane = tid & 63;
  const int g    = lane >> 4;
  const int c    = lane & 15;

  size_t batch = (size_t)blockIdx.x * 4 + w;
  const char* ub = (const char*)out + batch * 16384;  // padded-triangle u
  char* ys = smem + w * 4096;

  // direct global frag loads (each u element read exactly once)
  bf16x8 f0, f1, f2, f3, f2b, f3b;
#pragma unroll
  for (int ti = 0; ti < 4; ++ti) {
    int j = ti * 16 + c;
    int Q = j >> 3, s = j & 7;
    int ro = 16 * (4 * Q * (Q + 1) + s * (Q + 1));
    bf16x8 fa = *(const bf16x8*)(ub + ro + g * 16);
    if (ti == 0) f0 = zsel(fa, g * 8 <= j);
    if (ti == 1) f1 = zsel(fa, g * 8 <= j);
    if (ti == 2) f2 = fa;
    if (ti == 3) f3 = fa;
    if (ti >= 2) {
      bf16x8 fb = *(const bf16x8*)(ub + ro + 64 + g * 16);
      fb = zsel(fb, 32 + g * 8 <= j);
      if (ti == 2) f2b = fb;
      else         f3b = fb;
    }
  }

  bf16x8 fA[4] = {f0, f1, f2, f3};
  f32x4 acc[4][4];
#pragma unroll
  for (int ti = 0; ti < 4; ++ti)
#pragma unroll
    for (int tj = 0; tj < 4; ++tj) {
      f32x4 z = {0.f, 0.f, 0.f, 0.f};
      acc[ti][tj] = MFMA16(fA[ti], fA[tj], z);
    }
  acc[2][2] = MFMA16(f2b, f2b, acc[2][2]);
  acc[2][3] = MFMA16(f2b, f3b, acc[2][3]);
  acc[3][2] = MFMA16(f3b, f2b, acc[3][2]);
  acc[3][3] = MFMA16(f3b, f3b, acc[3][3]);

  // y write: stage 4KB (one ti-stripe) in LDS, store 1KB-contiguous dwordx4
  char* yb = (char*)out + batch * 16384;
#pragma unroll
  for (int ti = 0; ti < 4; ++ti) {
#pragma unroll
    for (int tj = 0; tj < 4; ++tj)
#pragma unroll
      for (int r = 0; r < 4; ++r)
        *(float*)(ys + (g * 4 + r) * 256 + (tj * 16 + c) * 4) = acc[ti][tj][r];
#pragma unroll
    for (int ii = 0; ii < 4; ++ii) {
      f32x4 v = *(const f32x4*)(ys + ii * 1024 + lane * 16);
      *(f32x4*)(yb + ti * 4096 + ii * 1024 + lane * 16) = v;
    }
  }
}

extern "C" void kernel_launch(void* const* d_in, const int* in_sizes, int n_in,
                              void* d_out, int out_size, void* d_ws, size_t ws_size,
                              hipStream_t stream) {
  (void)in_sizes; (void)n_in; (void)out_size; (void)ws_size;
  const float* x  = (const float*)d_in[0];
  const float* W1 = (const float*)d_in[1];
  const float* b1 = (const float*)d_in[2];
  const float* W2 = (const float*)d_in[3];
  const float* b2 = (const float*)d_in[4];
  const float* W3 = (const float*)d_in[5];
  const float* b3 = (const float*)d_in[6];
  char* wsb = (char*)d_ws;   // needs 1,352,704 B
  float* out = (float*)d_out;

  prep_kernel<<<1317, 512, 0, stream>>>(W1, W2, W3, b3, wsb);

  hipFuncSetAttribute((const void*)hm_mlp_kernel,
                      hipFuncAttributeMaxDynamicSharedMemorySize, 73984);
  hm_mlp_kernel<<<2048, 512, 73984, stream>>>(x, b1, b2, wsb, out);

  hm_gram_kernel<<<8192, 256, 16384, stream>>>(out);
}

// Round 6
// 441.837 us; speedup vs baseline: 1.0041x; 1.0028x over previous
//
#include <hip/hip_runtime.h>

// HamiltonianMetric: y[b] = u^T u, u = scatter(tanh(MLP(x))).
// R6: stage-3 pipeline enforced with __builtin_amdgcn_sched_barrier(0)
// between the prefetch-load group and the MFMA cluster (R4/R5 proved the
// machine scheduler sinks the loads below the compute; the asm use-anchor
// alone cannot prevent that). Loads now stay in flight across the compute.

typedef __bf16 bf16_t;
typedef bf16_t bf16x8 __attribute__((ext_vector_type(8)));
typedef float  f32x4  __attribute__((ext_vector_type(4)));

#define MFMA16(a, b, c) __builtin_amdgcn_mfma_f32_16x16x32_bf16((a), (b), (c), 0, 0, 0)

constexpr int SLOT = 4624;  // LDS slot stride (4608 data + 16 pad)
constexpr int USZ  = 4608;  // bytes of padded triangle per batch

__device__ __forceinline__ float fast_tanh(float x) {
  float cx = fminf(fmaxf(x, -30.0f), 30.0f);
  float t  = __expf(2.0f * cx);
  return (t - 1.0f) * __builtin_amdgcn_rcpf(t + 1.0f);
}

__device__ __forceinline__ bf16x8 zsel(bf16x8 f, bool keep) {
  union { bf16x8 v; unsigned int u[4]; } x;
  x.v = f;
  unsigned m = keep ? 0xFFFFFFFFu : 0u;
#pragma unroll
  for (int p = 0; p < 4; ++p) x.u[p] &= m;
  return x.v;
}

// padded position p -> (j, k): row j has j+1 valid entries, padded to 8-mult
__device__ __forceinline__ void decode_p(int p, int& j, int& k) {
  int cc = p >> 3, e = p & 7;
  int b = 0;
  while (b < 7 && cc >= 4 * (b + 1) * (b + 2)) ++b;
  int rl  = b + 1;
  int rem = cc - 4 * b * (b + 1);
  j = 8 * b + rem / rl;
  k = (rem % rl) * 8 + e;
}

// ws: [0,16384) W1t[256][64] | [16384,81920) W2t[256][256] |
//     [81920,671744) W3p[2304][256] | byte 1343488: b3p[2304] f32
__global__ void prep_kernel(const float* __restrict__ W1, const float* __restrict__ W2,
                            const float* __restrict__ W3, const float* __restrict__ b3,
                            char* __restrict__ wsb) {
  int tid = blockIdx.x * 512 + threadIdx.x;
  bf16_t* ws = (bf16_t*)wsb;
  if (tid < 16384) {
    int n = tid >> 6, k = tid & 63;
    ws[tid] = (bf16_t)W1[k * 256 + n];
  } else if (tid < 81920) {
    int m = tid - 16384;
    int n = m >> 8, k = m & 255;
    ws[tid] = (bf16_t)W2[k * 256 + n];
  } else if (tid < 671744) {
    int m = tid - 81920;
    int p = m >> 8, kcol = m & 255;
    int j, k;
    decode_p(p, j, k);
    float v = 0.f;
    if (k <= j) {
      int n_ref = (k == j) ? j : (64 + k * 63 - (k * (k - 1)) / 2 + j - k - 1);
      v = W3[kcol * 2080 + n_ref];
    }
    ws[tid] = (bf16_t)v;
  } else if (tid < 674048) {
    int p = tid - 671744;
    int j, k;
    decode_p(p, j, k);
    float v = 0.f;
    if (k <= j) {
      int n_ref = (k == j) ? j : (64 + k * 63 - (k * (k - 1)) / 2 + j - k - 1);
      v = b3[n_ref];
    }
    ((float*)(wsb + 1343488))[p] = v;
  }
}

// ---------------- kernel 1: MLP, 16 batches/block ----------------
__global__ void __launch_bounds__(512, 4)
hm_mlp_kernel(const float* __restrict__ x, const float* __restrict__ b1,
              const float* __restrict__ b2, const char* __restrict__ wsb,
              float* __restrict__ out) {
  extern __shared__ char smem[];  // 73984 B: 16 uT slots
  const int tid  = threadIdx.x;
  const int w    = tid >> 6;
  const int lane = tid & 63;
  const int g    = lane >> 4;
  const int c    = lane & 15;
  const int blk  = blockIdx.x;

  const bf16_t* W1t = (const bf16_t*)wsb;
  const bf16_t* W2t = W1t + 16384;
  const bf16_t* W3p = W1t + 81920;
  const float*  b3p = (const float*)(wsb + 1343488);

  char* xs  = smem;          // [16][64]  bf16, swz
  char* h1s = smem + 4096;   // [16][256] bf16, swz
  char* h2s = smem + 16384;  // [16][256] bf16, swz

  if (tid < 256) {
    f32x4 v = *(const f32x4*)(x + (size_t)blk * 1024 + tid * 4);
    int row = tid >> 4, col = (tid & 15) * 4;
    union { bf16_t b[4]; unsigned long long u; } pk;
    pk.b[0] = (bf16_t)v[0]; pk.b[1] = (bf16_t)v[1];
    pk.b[2] = (bf16_t)v[2]; pk.b[3] = (bf16_t)v[3];
    *(unsigned long long*)(xs + ((row * 128 + col * 2) ^ ((row & 7) << 4))) = pk.u;
  }
  __syncthreads();

  // stage 1
  {
    bf16x8 a0 = *(const bf16x8*)(xs + ((c * 128 + g * 16) ^ ((c & 7) << 4)));
    bf16x8 a1 = *(const bf16x8*)(xs + ((c * 128 + 64 + g * 16) ^ ((c & 7) << 4)));
#pragma unroll
    for (int ni = 0; ni < 2; ++ni) {
      int n = (w * 2 + ni) * 16 + c;
      bf16x8 bw0 = *(const bf16x8*)(W1t + n * 64 + g * 8);
      bf16x8 bw1 = *(const bf16x8*)(W1t + n * 64 + 32 + g * 8);
      f32x4 acc = {0.f, 0.f, 0.f, 0.f};
      acc = MFMA16(a0, bw0, acc);
      acc = MFMA16(a1, bw1, acc);
      float bias = b1[n];
#pragma unroll
      for (int r = 0; r < 4; ++r) {
        int row = g * 4 + r;
        float v = fast_tanh(acc[r] + bias);
        *(bf16_t*)(h1s + ((row * 512 + n * 2) ^ ((row & 7) << 4))) = (bf16_t)v;
      }
    }
  }
  __syncthreads();

  // stage 2
#pragma unroll
  for (int ni = 0; ni < 2; ++ni) {
    int n = (w * 2 + ni) * 16 + c;
    f32x4 acc0 = {0.f, 0.f, 0.f, 0.f}, acc1 = {0.f, 0.f, 0.f, 0.f};
#pragma unroll
    for (int kk = 0; kk < 8; kk += 2) {
      bf16x8 a0 = *(const bf16x8*)(h1s + ((c * 512 + kk * 64 + g * 16) ^ ((c & 7) << 4)));
      bf16x8 a1 = *(const bf16x8*)(h1s + ((c * 512 + (kk + 1) * 64 + g * 16) ^ ((c & 7) << 4)));
      bf16x8 bw0 = *(const bf16x8*)(W2t + n * 256 + kk * 32 + g * 8);
      bf16x8 bw1 = *(const bf16x8*)(W2t + n * 256 + (kk + 1) * 32 + g * 8);
      acc0 = MFMA16(a0, bw0, acc0);
      acc1 = MFMA16(a1, bw1, acc1);
    }
    f32x4 acc = acc0 + acc1;
    float bias = b2[n];
#pragma unroll
    for (int r = 0; r < 4; ++r) {
      int row = g * 4 + r;
      float v = fast_tanh(acc[r] + bias);
      *(bf16_t*)(h2s + ((row * 512 + n * 2) ^ ((row & 7) << 4))) = (bf16_t)v;
    }
  }
  __syncthreads();

  // ---- stage 3: sched_barrier-enforced software pipeline, 18 tiles/wave ----
  {
    bf16x8 a0 = *(const bf16x8*)(h2s + ((c * 512 + 0 * 64 + g * 16) ^ ((c & 7) << 4)));
    bf16x8 a1 = *(const bf16x8*)(h2s + ((c * 512 + 1 * 64 + g * 16) ^ ((c & 7) << 4)));
    bf16x8 a2 = *(const bf16x8*)(h2s + ((c * 512 + 2 * 64 + g * 16) ^ ((c & 7) << 4)));
    bf16x8 a3 = *(const bf16x8*)(h2s + ((c * 512 + 3 * 64 + g * 16) ^ ((c & 7) << 4)));
    bf16x8 a4 = *(const bf16x8*)(h2s + ((c * 512 + 4 * 64 + g * 16) ^ ((c & 7) << 4)));
    bf16x8 a5 = *(const bf16x8*)(h2s + ((c * 512 + 5 * 64 + g * 16) ^ ((c & 7) << 4)));
    bf16x8 a6 = *(const bf16x8*)(h2s + ((c * 512 + 6 * 64 + g * 16) ^ ((c & 7) << 4)));
    bf16x8 a7 = *(const bf16x8*)(h2s + ((c * 512 + 7 * 64 + g * 16) ^ ((c & 7) << 4)));
    __syncthreads();  // arena now free: 16 uT slots

    // pin A-fragments live in registers across the whole loop
    asm volatile("" : "+v"(a0), "+v"(a1), "+v"(a2), "+v"(a3),
                      "+v"(a4), "+v"(a5), "+v"(a6), "+v"(a7));

    int p0 = (w * 16 + c);
    const bf16_t* bp = W3p + p0 * 256 + g * 8;
    bf16x8 c0 = *(const bf16x8*)(bp + 0);
    bf16x8 c1 = *(const bf16x8*)(bp + 32);
    bf16x8 c2 = *(const bf16x8*)(bp + 64);
    bf16x8 c3 = *(const bf16x8*)(bp + 96);
    bf16x8 c4 = *(const bf16x8*)(bp + 128);
    bf16x8 c5 = *(const bf16x8*)(bp + 160);
    bf16x8 c6 = *(const bf16x8*)(bp + 192);
    bf16x8 c7 = *(const bf16x8*)(bp + 224);
    float  cb = b3p[p0];
    char*  tw = smem + (g * 4) * SLOT;

#pragma unroll 1
    for (int it = 0; it < 18; ++it) {
      // issue next tile's loads; the sched_barrier below FORCES them to be
      // emitted before the MFMA cluster (they stay in flight across it).
      int itn = (it < 17) ? (it + 1) : 17;  // last iter: redundant reload
      int pn  = (w + itn * 8) * 16 + c;
      const bf16_t* np = W3p + pn * 256 + g * 8;
      bf16x8 n0 = *(const bf16x8*)(np + 0);
      bf16x8 n1 = *(const bf16x8*)(np + 32);
      bf16x8 n2 = *(const bf16x8*)(np + 64);
      bf16x8 n3 = *(const bf16x8*)(np + 96);
      bf16x8 n4 = *(const bf16x8*)(np + 128);
      bf16x8 n5 = *(const bf16x8*)(np + 160);
      bf16x8 n6 = *(const bf16x8*)(np + 192);
      bf16x8 n7 = *(const bf16x8*)(np + 224);
      float  nb = b3p[pn];

      __builtin_amdgcn_sched_barrier(0);  // hard fence: loads above, compute below

      // compute current tile (c regs) while n-loads are in flight
      f32x4 acc0 = {0.f, 0.f, 0.f, 0.f}, acc1 = {0.f, 0.f, 0.f, 0.f};
      acc0 = MFMA16(a0, c0, acc0); acc1 = MFMA16(a1, c1, acc1);
      acc0 = MFMA16(a2, c2, acc0); acc1 = MFMA16(a3, c3, acc1);
      acc0 = MFMA16(a4, c4, acc0); acc1 = MFMA16(a5, c5, acc1);
      acc0 = MFMA16(a6, c6, acc0); acc1 = MFMA16(a7, c7, acc1);
      f32x4 acc = acc0 + acc1;

      int p = (w + it * 8) * 16 + c;
#pragma unroll
      for (int r = 0; r < 4; ++r) {
        float v = fast_tanh(acc[r] + cb);
        *(bf16_t*)(tw + r * SLOT + p * 2) = (bf16_t)v;
      }

      // wait for n-loads lands HERE (first use), after the compute above
      asm volatile("" :: "v"(n0), "v"(n1), "v"(n2), "v"(n3),
                         "v"(n4), "v"(n5), "v"(n6), "v"(n7), "v"(nb));

      // rotate pipeline registers
      c0 = n0; c1 = n1; c2 = n2; c3 = n3;
      c4 = n4; c5 = n5; c6 = n6; c7 = n7; cb = nb;
    }
  }
  __syncthreads();

  // copy-out: slot m -> first 4608 B of batch (blk*16+m)'s output region
#pragma unroll
  for (int m2 = 0; m2 < 2; ++m2) {
    int m = w * 2 + m2;
    const char* s = smem + m * SLOT;
    char* dst = (char*)out + (size_t)(blk * 16 + m) * 16384;
#pragma unroll
    for (int i = 0; i < 5; ++i) {
      int off = i * 1024 + lane * 16;
      if (off < USZ) *(f32x4*)(dst + off) = *(const f32x4*)(s + off);
    }
  }
}

// ---------------- kernel 2: Gram, 1 batch per wave, no barriers ----------------
__global__ void __launch_bounds__(256, 4)
hm_gram_kernel(float* __restrict__ out) {
  extern __shared__ char smem[];  // 4 waves x 4096 B y-staging
  const int tid  = threadIdx.x;
  const int w    = tid >> 6;
  const int lane = tid & 63;
  const int g    = lane >> 4;
  const int c    = lane & 15;

  size_t batch = (size_t)blockIdx.x * 4 + w;
  const char* ub = (const char*)out + batch * 16384;  // padded-triangle u
  char* ys = smem + w * 4096;

  // direct global frag loads (each u element read exactly once)
  bf16x8 f0, f1, f2, f3, f2b, f3b;
#pragma unroll
  for (int ti = 0; ti < 4; ++ti) {
    int j = ti * 16 + c;
    int Q = j >> 3, s = j & 7;
    int ro = 16 * (4 * Q * (Q + 1) + s * (Q + 1));
    bf16x8 fa = *(const bf16x8*)(ub + ro + g * 16);
    if (ti == 0) f0 = zsel(fa, g * 8 <= j);
    if (ti == 1) f1 = zsel(fa, g * 8 <= j);
    if (ti == 2) f2 = fa;
    if (ti == 3) f3 = fa;
    if (ti >= 2) {
      bf16x8 fb = *(const bf16x8*)(ub + ro + 64 + g * 16);
      fb = zsel(fb, 32 + g * 8 <= j);
      if (ti == 2) f2b = fb;
      else         f3b = fb;
    }
  }

  bf16x8 fA[4] = {f0, f1, f2, f3};
  f32x4 acc[4][4];
#pragma unroll
  for (int ti = 0; ti < 4; ++ti)
#pragma unroll
    for (int tj = 0; tj < 4; ++tj) {
      f32x4 z = {0.f, 0.f, 0.f, 0.f};
      acc[ti][tj] = MFMA16(fA[ti], fA[tj], z);
    }
  acc[2][2] = MFMA16(f2b, f2b, acc[2][2]);
  acc[2][3] = MFMA16(f2b, f3b, acc[2][3]);
  acc[3][2] = MFMA16(f3b, f2b, acc[3][2]);
  acc[3][3] = MFMA16(f3b, f3b, acc[3][3]);

  // y write: stage 4KB (one ti-stripe) in LDS, store 1KB-contiguous dwordx4
  char* yb = (char*)out + batch * 16384;
#pragma unroll
  for (int ti = 0; ti < 4; ++ti) {
#pragma unroll
    for (int tj = 0; tj < 4; ++tj)
#pragma unroll
      for (int r = 0; r < 4; ++r)
        *(float*)(ys + (g * 4 + r) * 256 + (tj * 16 + c) * 4) = acc[ti][tj][r];
#pragma unroll
    for (int ii = 0; ii < 4; ++ii) {
      f32x4 v = *(const f32x4*)(ys + ii * 1024 + lane * 16);
      *(f32x4*)(yb + ti * 4096 + ii * 1024 + lane * 16) = v;
    }
  }
}

extern "C" void kernel_launch(void* const* d_in, const int* in_sizes, int n_in,
                              void* d_out, int out_size, void* d_ws, size_t ws_size,
                              hipStream_t stream) {
  (void)in_sizes; (void)n_in; (void)out_size; (void)ws_size;
  const float* x  = (const float*)d_in[0];
  const float* W1 = (const float*)d_in[1];
  const float* b1 = (const float*)d_in[2];
  const float* W2 = (const float*)d_in[3];
  const float* b2 = (const float*)d_in[4];
  const float* W3 = (const float*)d_in[5];
  const float* b3 = (const float*)d_in[6];
  char* wsb = (char*)d_ws;   // needs 1,352,704 B
  float* out = (float*)d_out;

  prep_kernel<<<1317, 512, 0, stream>>>(W1, W2, W3, b3, wsb);

  hipFuncSetAttribute((const void*)hm_mlp_kernel,
                      hipFuncAttributeMaxDynamicSharedMemorySize, 73984);
  hm_mlp_kernel<<<2048, 512, 73984, stream>>>(x, b1, b2, wsb, out);

  hm_gram_kernel<<<8192, 256, 16384, stream>>>(out);
}

// Round 7
// 427.664 us; speedup vs baseline: 1.0374x; 1.0331x over previous
//
#include <hip/hip_runtime.h>

// HamiltonianMetric: y[b] = u^T u, u = scatter(tanh(MLP(x))).
// R7: stage-3 W3 loads as inline-asm global_load_dwordx4 with manual counted
// s_waitcnt vmcnt(9) (AITER pattern). R4-R6 proved the compiler collapses any
// source-level register pipeline (rotation is a rename; sched_barrier is
// IntrNoMem at IR level). Volatile asm loads cannot be merged/renamed/sunk.

typedef __bf16 bf16_t;
typedef bf16_t bf16x8 __attribute__((ext_vector_type(8)));
typedef float  f32x4  __attribute__((ext_vector_type(4)));

#define MFMA16(a, b, c) __builtin_amdgcn_mfma_f32_16x16x32_bf16((a), (b), (c), 0, 0, 0)

constexpr int SLOT = 4624;  // LDS slot stride (4608 data + 16 pad)
constexpr int USZ  = 4608;  // bytes of padded triangle per batch

__device__ __forceinline__ float fast_tanh(float x) {
  float cx = fminf(fmaxf(x, -30.0f), 30.0f);
  float t  = __expf(2.0f * cx);
  return (t - 1.0f) * __builtin_amdgcn_rcpf(t + 1.0f);
}

__device__ __forceinline__ bf16x8 zsel(bf16x8 f, bool keep) {
  union { bf16x8 v; unsigned int u[4]; } x;
  x.v = f;
  unsigned m = keep ? 0xFFFFFFFFu : 0u;
#pragma unroll
  for (int p = 0; p < 4; ++p) x.u[p] &= m;
  return x.v;
}

// padded position p -> (j, k): row j has j+1 valid entries, padded to 8-mult
__device__ __forceinline__ void decode_p(int p, int& j, int& k) {
  int cc = p >> 3, e = p & 7;
  int b = 0;
  while (b < 7 && cc >= 4 * (b + 1) * (b + 2)) ++b;
  int rl  = b + 1;
  int rem = cc - 4 * b * (b + 1);
  j = 8 * b + rem / rl;
  k = (rem % rl) * 8 + e;
}

// ws: [0,16384) W1t[256][64] | [16384,81920) W2t[256][256] |
//     [81920,671744) W3p[2304][256] | byte 1343488: b3p[2304] f32
__global__ void prep_kernel(const float* __restrict__ W1, const float* __restrict__ W2,
                            const float* __restrict__ W3, const float* __restrict__ b3,
                            char* __restrict__ wsb) {
  int tid = blockIdx.x * 512 + threadIdx.x;
  bf16_t* ws = (bf16_t*)wsb;
  if (tid < 16384) {
    int n = tid >> 6, k = tid & 63;
    ws[tid] = (bf16_t)W1[k * 256 + n];
  } else if (tid < 81920) {
    int m = tid - 16384;
    int n = m >> 8, k = m & 255;
    ws[tid] = (bf16_t)W2[k * 256 + n];
  } else if (tid < 671744) {
    int m = tid - 81920;
    int p = m >> 8, kcol = m & 255;
    int j, k;
    decode_p(p, j, k);
    float v = 0.f;
    if (k <= j) {
      int n_ref = (k == j) ? j : (64 + k * 63 - (k * (k - 1)) / 2 + j - k - 1);
      v = W3[kcol * 2080 + n_ref];
    }
    ws[tid] = (bf16_t)v;
  } else if (tid < 674048) {
    int p = tid - 671744;
    int j, k;
    decode_p(p, j, k);
    float v = 0.f;
    if (k <= j) {
      int n_ref = (k == j) ? j : (64 + k * 63 - (k * (k - 1)) / 2 + j - k - 1);
      v = b3[n_ref];
    }
    ((float*)(wsb + 1343488))[p] = v;
  }
}

// ---------------- kernel 1: MLP, 16 batches/block ----------------
__global__ void __launch_bounds__(512, 4)
hm_mlp_kernel(const float* __restrict__ x, const float* __restrict__ b1,
              const float* __restrict__ b2, const char* __restrict__ wsb,
              float* __restrict__ out) {
  extern __shared__ char smem[];  // 73984 B: 16 uT slots
  const int tid  = threadIdx.x;
  const int w    = tid >> 6;
  const int lane = tid & 63;
  const int g    = lane >> 4;
  const int c    = lane & 15;
  const int blk  = blockIdx.x;

  const bf16_t* W1t = (const bf16_t*)wsb;
  const bf16_t* W2t = W1t + 16384;
  const bf16_t* W3p = W1t + 81920;
  const float*  b3p = (const float*)(wsb + 1343488);

  char* xs  = smem;          // [16][64]  bf16, swz
  char* h1s = smem + 4096;   // [16][256] bf16, swz
  char* h2s = smem + 16384;  // [16][256] bf16, swz

  if (tid < 256) {
    f32x4 v = *(const f32x4*)(x + (size_t)blk * 1024 + tid * 4);
    int row = tid >> 4, col = (tid & 15) * 4;
    union { bf16_t b[4]; unsigned long long u; } pk;
    pk.b[0] = (bf16_t)v[0]; pk.b[1] = (bf16_t)v[1];
    pk.b[2] = (bf16_t)v[2]; pk.b[3] = (bf16_t)v[3];
    *(unsigned long long*)(xs + ((row * 128 + col * 2) ^ ((row & 7) << 4))) = pk.u;
  }
  __syncthreads();

  // stage 1
  {
    bf16x8 a0 = *(const bf16x8*)(xs + ((c * 128 + g * 16) ^ ((c & 7) << 4)));
    bf16x8 a1 = *(const bf16x8*)(xs + ((c * 128 + 64 + g * 16) ^ ((c & 7) << 4)));
#pragma unroll
    for (int ni = 0; ni < 2; ++ni) {
      int n = (w * 2 + ni) * 16 + c;
      bf16x8 bw0 = *(const bf16x8*)(W1t + n * 64 + g * 8);
      bf16x8 bw1 = *(const bf16x8*)(W1t + n * 64 + 32 + g * 8);
      f32x4 acc = {0.f, 0.f, 0.f, 0.f};
      acc = MFMA16(a0, bw0, acc);
      acc = MFMA16(a1, bw1, acc);
      float bias = b1[n];
#pragma unroll
      for (int r = 0; r < 4; ++r) {
        int row = g * 4 + r;
        float v = fast_tanh(acc[r] + bias);
        *(bf16_t*)(h1s + ((row * 512 + n * 2) ^ ((row & 7) << 4))) = (bf16_t)v;
      }
    }
  }
  __syncthreads();

  // stage 2
#pragma unroll
  for (int ni = 0; ni < 2; ++ni) {
    int n = (w * 2 + ni) * 16 + c;
    f32x4 acc0 = {0.f, 0.f, 0.f, 0.f}, acc1 = {0.f, 0.f, 0.f, 0.f};
#pragma unroll
    for (int kk = 0; kk < 8; kk += 2) {
      bf16x8 a0 = *(const bf16x8*)(h1s + ((c * 512 + kk * 64 + g * 16) ^ ((c & 7) << 4)));
      bf16x8 a1 = *(const bf16x8*)(h1s + ((c * 512 + (kk + 1) * 64 + g * 16) ^ ((c & 7) << 4)));
      bf16x8 bw0 = *(const bf16x8*)(W2t + n * 256 + kk * 32 + g * 8);
      bf16x8 bw1 = *(const bf16x8*)(W2t + n * 256 + (kk + 1) * 32 + g * 8);
      acc0 = MFMA16(a0, bw0, acc0);
      acc1 = MFMA16(a1, bw1, acc1);
    }
    f32x4 acc = acc0 + acc1;
    float bias = b2[n];
#pragma unroll
    for (int r = 0; r < 4; ++r) {
      int row = g * 4 + r;
      float v = fast_tanh(acc[r] + bias);
      *(bf16_t*)(h2s + ((row * 512 + n * 2) ^ ((row & 7) << 4))) = (bf16_t)v;
    }
  }
  __syncthreads();

  // ---- stage 3: inline-asm loads + manual counted vmcnt pipeline ----
  {
    bf16x8 a0 = *(const bf16x8*)(h2s + ((c * 512 + 0 * 64 + g * 16) ^ ((c & 7) << 4)));
    bf16x8 a1 = *(const bf16x8*)(h2s + ((c * 512 + 1 * 64 + g * 16) ^ ((c & 7) << 4)));
    bf16x8 a2 = *(const bf16x8*)(h2s + ((c * 512 + 2 * 64 + g * 16) ^ ((c & 7) << 4)));
    bf16x8 a3 = *(const bf16x8*)(h2s + ((c * 512 + 3 * 64 + g * 16) ^ ((c & 7) << 4)));
    bf16x8 a4 = *(const bf16x8*)(h2s + ((c * 512 + 4 * 64 + g * 16) ^ ((c & 7) << 4)));
    bf16x8 a5 = *(const bf16x8*)(h2s + ((c * 512 + 5 * 64 + g * 16) ^ ((c & 7) << 4)));
    bf16x8 a6 = *(const bf16x8*)(h2s + ((c * 512 + 6 * 64 + g * 16) ^ ((c & 7) << 4)));
    bf16x8 a7 = *(const bf16x8*)(h2s + ((c * 512 + 7 * 64 + g * 16) ^ ((c & 7) << 4)));
    __syncthreads();  // arena now free: 16 uT slots

    char* tw = smem + (g * 4) * SLOT;

    bf16x8 A0, A1, A2, A3, A4, A5, A6, A7; float Ab;
    bf16x8 B0, B1, B2, B3, B4, B5, B6, B7; float Bb;

#define ISSUE_T(S, TI)                                                          \
  do {                                                                          \
    int pn_ = ((w) + (TI) * 8) * 16 + c;                                        \
    const bf16_t* np_ = W3p + pn_ * 256 + g * 8;                                \
    asm volatile("global_load_dwordx4 %0, %1, off" : "=v"(S##0) : "v"(np_));        \
    asm volatile("global_load_dwordx4 %0, %1, off" : "=v"(S##1) : "v"(np_ + 32));   \
    asm volatile("global_load_dwordx4 %0, %1, off" : "=v"(S##2) : "v"(np_ + 64));   \
    asm volatile("global_load_dwordx4 %0, %1, off" : "=v"(S##3) : "v"(np_ + 96));   \
    asm volatile("global_load_dwordx4 %0, %1, off" : "=v"(S##4) : "v"(np_ + 128));  \
    asm volatile("global_load_dwordx4 %0, %1, off" : "=v"(S##5) : "v"(np_ + 160));  \
    asm volatile("global_load_dwordx4 %0, %1, off" : "=v"(S##6) : "v"(np_ + 192));  \
    asm volatile("global_load_dwordx4 %0, %1, off" : "=v"(S##7) : "v"(np_ + 224));  \
    asm volatile("global_load_dword %0, %1, off"   : "=v"(S##b) : "v"(b3p + pn_));  \
  } while (0)

#define WAIT_N(N)                                          \
  do {                                                     \
    asm volatile("s_waitcnt vmcnt(" #N ")" ::: "memory");  \
    __builtin_amdgcn_sched_barrier(0);                     \
  } while (0)

#define COMP_T(S, TI)                                                    \
  do {                                                                   \
    f32x4 acc0 = {S##b, S##b, S##b, S##b};  /* bias: rows share column */\
    f32x4 acc1 = {0.f, 0.f, 0.f, 0.f};                                   \
    acc0 = MFMA16(a0, S##0, acc0); acc1 = MFMA16(a1, S##1, acc1);        \
    acc0 = MFMA16(a2, S##2, acc0); acc1 = MFMA16(a3, S##3, acc1);        \
    acc0 = MFMA16(a4, S##4, acc0); acc1 = MFMA16(a5, S##5, acc1);        \
    acc0 = MFMA16(a6, S##6, acc0); acc1 = MFMA16(a7, S##7, acc1);        \
    f32x4 accs = acc0 + acc1;                                            \
    int p_ = ((w) + (TI) * 8) * 16 + c;                                  \
    _Pragma("unroll")                                                    \
    for (int r_ = 0; r_ < 4; ++r_) {                                     \
      float v_ = fast_tanh(accs[r_]);                                    \
      *(bf16_t*)(tw + r_ * SLOT + p_ * 2) = (bf16_t)v_;                  \
    }                                                                    \
  } while (0)

    ISSUE_T(A, 0);
#pragma unroll 1
    for (int pr = 0; pr < 8; ++pr) {
      ISSUE_T(B, 2 * pr + 1);
      WAIT_N(9);            // tile 2pr (A) complete; B's 9 still in flight
      COMP_T(A, 2 * pr);
      ISSUE_T(A, 2 * pr + 2);
      WAIT_N(9);            // tile 2pr+1 (B) complete; A's 9 in flight
      COMP_T(B, 2 * pr + 1);
    }
    ISSUE_T(B, 17);
    WAIT_N(9);
    COMP_T(A, 16);
    WAIT_N(0);
    COMP_T(B, 17);

#undef ISSUE_T
#undef WAIT_N
#undef COMP_T
  }
  __syncthreads();

  // copy-out: slot m -> first 4608 B of batch (blk*16+m)'s output region
#pragma unroll
  for (int m2 = 0; m2 < 2; ++m2) {
    int m = w * 2 + m2;
    const char* s = smem + m * SLOT;
    char* dst = (char*)out + (size_t)(blk * 16 + m) * 16384;
#pragma unroll
    for (int i = 0; i < 5; ++i) {
      int off = i * 1024 + lane * 16;
      if (off < USZ) *(f32x4*)(dst + off) = *(const f32x4*)(s + off);
    }
  }
}

// ---------------- kernel 2: Gram, 1 batch per wave, no barriers ----------------
__global__ void __launch_bounds__(256, 4)
hm_gram_kernel(float* __restrict__ out) {
  extern __shared__ char smem[];  // 4 waves x 4096 B y-staging
  const int tid  = threadIdx.x;
  const int w    = tid >> 6;
  const int lane = tid & 63;
  const int g    = lane >> 4;
  const int c    = lane & 15;

  size_t batch = (size_t)blockIdx.x * 4 + w;
  const char* ub = (const char*)out + batch * 16384;  // padded-triangle u
  char* ys = smem + w * 4096;

  // direct global frag loads (each u element read exactly once)
  bf16x8 f0, f1, f2, f3, f2b, f3b;
#pragma unroll
  for (int ti = 0; ti < 4; ++ti) {
    int j = ti * 16 + c;
    int Q = j >> 3, s = j & 7;
    int ro = 16 * (4 * Q * (Q + 1) + s * (Q + 1));
    bf16x8 fa = *(const bf16x8*)(ub + ro + g * 16);
    if (ti == 0) f0 = zsel(fa, g * 8 <= j);
    if (ti == 1) f1 = zsel(fa, g * 8 <= j);
    if (ti == 2) f2 = fa;
    if (ti == 3) f3 = fa;
    if (ti >= 2) {
      bf16x8 fb = *(const bf16x8*)(ub + ro + 64 + g * 16);
      fb = zsel(fb, 32 + g * 8 <= j);
      if (ti == 2) f2b = fb;
      else         f3b = fb;
    }
  }

  bf16x8 fA[4] = {f0, f1, f2, f3};
  f32x4 acc[4][4];
#pragma unroll
  for (int ti = 0; ti < 4; ++ti)
#pragma unroll
    for (int tj = 0; tj < 4; ++tj) {
      f32x4 z = {0.f, 0.f, 0.f, 0.f};
      acc[ti][tj] = MFMA16(fA[ti], fA[tj], z);
    }
  acc[2][2] = MFMA16(f2b, f2b, acc[2][2]);
  acc[2][3] = MFMA16(f2b, f3b, acc[2][3]);
  acc[3][2] = MFMA16(f3b, f2b, acc[3][2]);
  acc[3][3] = MFMA16(f3b, f3b, acc[3][3]);

  // y write: stage 4KB (one ti-stripe) in LDS, store 1KB-contiguous dwordx4
  char* yb = (char*)out + batch * 16384;
#pragma unroll
  for (int ti = 0; ti < 4; ++ti) {
#pragma unroll
    for (int tj = 0; tj < 4; ++tj)
#pragma unroll
      for (int r = 0; r < 4; ++r)
        *(float*)(ys + (g * 4 + r) * 256 + (tj * 16 + c) * 4) = acc[ti][tj][r];
#pragma unroll
    for (int ii = 0; ii < 4; ++ii) {
      f32x4 v = *(const f32x4*)(ys + ii * 1024 + lane * 16);
      *(f32x4*)(yb + ti * 4096 + ii * 1024 + lane * 16) = v;
    }
  }
}

extern "C" void kernel_launch(void* const* d_in, const int* in_sizes, int n_in,
                              void* d_out, int out_size, void* d_ws, size_t ws_size,
                              hipStream_t stream) {
  (void)in_sizes; (void)n_in; (void)out_size; (void)ws_size;
  const float* x  = (const float*)d_in[0];
  const float* W1 = (const float*)d_in[1];
  const float* b1 = (const float*)d_in[2];
  const float* W2 = (const float*)d_in[3];
  const float* b2 = (const float*)d_in[4];
  const float* W3 = (const float*)d_in[5];
  const float* b3 = (const float*)d_in[6];
  char* wsb = (char*)d_ws;   // needs 1,352,704 B
  float* out = (float*)d_out;

  prep_kernel<<<1317, 512, 0, stream>>>(W1, W2, W3, b3, wsb);

  hipFuncSetAttribute((const void*)hm_mlp_kernel,
                      hipFuncAttributeMaxDynamicSharedMemorySize, 73984);
  hm_mlp_kernel<<<2048, 512, 73984, stream>>>(x, b1, b2, wsb, out);

  hm_gram_kernel<<<8192, 256, 16384, stream>>>(out);
}

// Round 9
// 276.741 us; speedup vs baseline: 1.6031x; 1.5454x over previous
//
#include <hip/hip_runtime.h>

// HamiltonianMetric: y[b] = u^T u, u = scatter(tanh(MLP(x))).
// R9 = R8 + epilogue fix (R8 dropped ISSUE_T(B,17) -> tile 17 computed from
// stale registers -> tail rows of u garbage). Structure unchanged:
//  - W3 tile-major+lane-major: one wave B-frag load = one contiguous 1KB burst
//  - 32 batches/block (1024 thr, 16 waves): W3 L2 traffic halved
//  - LDS 160KB: 32 u-slots x 4608 (XOR-swizzled) + h2 16KB

typedef __bf16 bf16_t;
typedef bf16_t bf16x8 __attribute__((ext_vector_type(8)));
typedef float  f32x4  __attribute__((ext_vector_type(4)));

#define MFMA16(a, b, c) __builtin_amdgcn_mfma_f32_16x16x32_bf16((a), (b), (c), 0, 0, 0)

constexpr int SLOT = 4608;    // bytes per uT slot (bank-aligned, XOR-swizzled)
constexpr int USZ  = 4608;    // bytes of padded triangle per batch
constexpr int H2OFF = 147456; // 32*SLOT; h2s lives at [147456,163840)

__device__ __forceinline__ float fast_tanh(float x) {
  float cx = fminf(fmaxf(x, -30.0f), 30.0f);
  float t  = __expf(2.0f * cx);
  return (t - 1.0f) * __builtin_amdgcn_rcpf(t + 1.0f);
}

__device__ __forceinline__ bf16x8 zsel(bf16x8 f, bool keep) {
  union { bf16x8 v; unsigned int u[4]; } x;
  x.v = f;
  unsigned m = keep ? 0xFFFFFFFFu : 0u;
#pragma unroll
  for (int p = 0; p < 4; ++p) x.u[p] &= m;
  return x.v;
}

// padded position p -> (j, k): row j has j+1 valid entries, padded to 8-mult
__device__ __forceinline__ void decode_p(int p, int& j, int& k) {
  int cc = p >> 3, e = p & 7;
  int b = 0;
  while (b < 7 && cc >= 4 * (b + 1) * (b + 2)) ++b;
  int rl  = b + 1;
  int rem = cc - 4 * b * (b + 1);
  j = 8 * b + rem / rl;
  k = (rem % rl) * 8 + e;
}

// ws: [0,16384) W1t[256n][64k] | [16384,81920) W2t[256n][256k] |
//     [81920,671744) W3q tile-major: [144 t][8 kk][64 lane][8 e]
//     byte 1343488: b3p[2304] f32 (permuted triangle bias, 0 in padding)
__global__ void prep_kernel(const float* __restrict__ W1, const float* __restrict__ W2,
                            const float* __restrict__ W3, const float* __restrict__ b3,
                            char* __restrict__ wsb) {
  int tid = blockIdx.x * 512 + threadIdx.x;
  bf16_t* ws = (bf16_t*)wsb;
  if (tid < 16384) {
    int n = tid >> 6, k = tid & 63;
    ws[tid] = (bf16_t)W1[k * 256 + n];
  } else if (tid < 81920) {
    int m = tid - 16384;
    int n = m >> 8, k = m & 255;
    ws[tid] = (bf16_t)W2[k * 256 + n];
  } else if (tid < 671744) {
    int m = tid - 81920;
    int t  = m >> 12;
    int r  = m & 4095;
    int kk = r >> 9;
    int g  = (r >> 7) & 3;
    int c  = (r >> 3) & 15;
    int e  = r & 7;
    int p  = t * 16 + c;          // triangle position
    int k  = kk * 32 + g * 8 + e; // H-dim column
    int j, kd;
    decode_p(p, j, kd);
    float v = 0.f;
    if (kd <= j) {
      int n_ref = (kd == j) ? j : (64 + kd * 63 - (kd * (kd - 1)) / 2 + j - kd - 1);
      v = W3[k * 2080 + n_ref];
    }
    ws[tid] = (bf16_t)v;
  } else if (tid < 674048) {
    int p = tid - 671744;
    int j, kd;
    decode_p(p, j, kd);
    float v = 0.f;
    if (kd <= j) {
      int n_ref = (kd == j) ? j : (64 + kd * 63 - (kd * (kd - 1)) / 2 + j - kd - 1);
      v = b3[n_ref];
    }
    ((float*)(wsb + 1343488))[p] = v;
  }
}

// ---------------- kernel 1: MLP, 32 batches/block, 16 waves ----------------
__global__ void __launch_bounds__(1024, 4)
hm_mlp_kernel(const float* __restrict__ x, const float* __restrict__ b1,
              const float* __restrict__ b2, const char* __restrict__ wsb,
              float* __restrict__ out) {
  extern __shared__ char smem[];  // 163840 B
  const int tid  = threadIdx.x;
  const int w    = tid >> 6;    // wave 0..15
  const int wv   = w & 7;       // n-tile lane
  const int mt   = w >> 3;      // m-half (0/1): batches mt*16..mt*16+15
  const int lane = tid & 63;
  const int g    = lane >> 4;
  const int c    = lane & 15;
  const int blk  = blockIdx.x;

  const bf16_t* W1t = (const bf16_t*)wsb;
  const bf16_t* W2t = W1t + 16384;
  const bf16_t* W3q = W1t + 81920;
  const float*  b3p = (const float*)(wsb + 1343488);

  char* xs  = smem;          // [32][64]  bf16, swz (stage 1 only)
  char* h1s = smem + 8192;   // [32][256] bf16, swz (stages 1-2)
  char* h2s = smem + H2OFF;  // [32][256] bf16, swz (stages 2-3)

  // ---- load x: 32 rows x 64 f32 -> bf16 LDS ----
  if (tid < 512) {
    f32x4 v = *(const f32x4*)(x + (size_t)blk * 2048 + tid * 4);
    int row = tid >> 4, col = (tid & 15) * 4;
    union { bf16_t b[4]; unsigned long long u; } pk;
    pk.b[0] = (bf16_t)v[0]; pk.b[1] = (bf16_t)v[1];
    pk.b[2] = (bf16_t)v[2]; pk.b[3] = (bf16_t)v[3];
    *(unsigned long long*)(xs + ((row * 128 + col * 2) ^ ((row & 7) << 4))) = pk.u;
  }
  __syncthreads();

  // ---- stage 1: h1 = tanh(x @ W1 + b1); wave (mt, nt=wv*2+ni) ----
  {
    int arow = mt * 16 + c;
    bf16x8 a0 = *(const bf16x8*)(xs + ((arow * 128 + g * 16) ^ ((arow & 7) << 4)));
    bf16x8 a1 = *(const bf16x8*)(xs + ((arow * 128 + 64 + g * 16) ^ ((arow & 7) << 4)));
#pragma unroll
    for (int ni = 0; ni < 2; ++ni) {
      int n = (wv * 2 + ni) * 16 + c;
      bf16x8 bw0 = *(const bf16x8*)(W1t + n * 64 + g * 8);
      bf16x8 bw1 = *(const bf16x8*)(W1t + n * 64 + 32 + g * 8);
      f32x4 acc = {0.f, 0.f, 0.f, 0.f};
      acc = MFMA16(a0, bw0, acc);
      acc = MFMA16(a1, bw1, acc);
      float bias = b1[n];
#pragma unroll
      for (int r = 0; r < 4; ++r) {
        int row = mt * 16 + g * 4 + r;
        float v = fast_tanh(acc[r] + bias);
        *(bf16_t*)(h1s + ((row * 512 + n * 2) ^ ((row & 7) << 4))) = (bf16_t)v;
      }
    }
  }
  __syncthreads();

  // ---- stage 2: h2 = tanh(h1 @ W2 + b2) ----
#pragma unroll
  for (int ni = 0; ni < 2; ++ni) {
    int n = (wv * 2 + ni) * 16 + c;
    int arow = mt * 16 + c;
    f32x4 acc0 = {0.f, 0.f, 0.f, 0.f}, acc1 = {0.f, 0.f, 0.f, 0.f};
#pragma unroll
    for (int kk = 0; kk < 8; kk += 2) {
      bf16x8 a0 = *(const bf16x8*)(h1s + ((arow * 512 + kk * 64 + g * 16) ^ ((arow & 7) << 4)));
      bf16x8 a1 = *(const bf16x8*)(h1s + ((arow * 512 + (kk + 1) * 64 + g * 16) ^ ((arow & 7) << 4)));
      bf16x8 bw0 = *(const bf16x8*)(W2t + n * 256 + kk * 32 + g * 8);
      bf16x8 bw1 = *(const bf16x8*)(W2t + n * 256 + (kk + 1) * 32 + g * 8);
      acc0 = MFMA16(a0, bw0, acc0);
      acc1 = MFMA16(a1, bw1, acc1);
    }
    f32x4 acc = acc0 + acc1;
    float bias = b2[n];
#pragma unroll
    for (int r = 0; r < 4; ++r) {
      int row = mt * 16 + g * 4 + r;
      float v = fast_tanh(acc[r] + bias);
      *(bf16_t*)(h2s + ((row * 512 + n * 2) ^ ((row & 7) << 4))) = (bf16_t)v;
    }
  }
  __syncthreads();

  // ---- stage 3: t = tanh(h2 @ W3 + b3) -> 32 uT slots (XOR-swizzled) ----
  // h2s does NOT overlap the slot arena, so no barrier needed inside.
  {
    int arow = mt * 16 + c;
    bf16x8 a0 = *(const bf16x8*)(h2s + ((arow * 512 + 0 * 64 + g * 16) ^ ((arow & 7) << 4)));
    bf16x8 a1 = *(const bf16x8*)(h2s + ((arow * 512 + 1 * 64 + g * 16) ^ ((arow & 7) << 4)));
    bf16x8 a2 = *(const bf16x8*)(h2s + ((arow * 512 + 2 * 64 + g * 16) ^ ((arow & 7) << 4)));
    bf16x8 a3 = *(const bf16x8*)(h2s + ((arow * 512 + 3 * 64 + g * 16) ^ ((arow & 7) << 4)));
    bf16x8 a4 = *(const bf16x8*)(h2s + ((arow * 512 + 4 * 64 + g * 16) ^ ((arow & 7) << 4)));
    bf16x8 a5 = *(const bf16x8*)(h2s + ((arow * 512 + 5 * 64 + g * 16) ^ ((arow & 7) << 4)));
    bf16x8 a6 = *(const bf16x8*)(h2s + ((arow * 512 + 6 * 64 + g * 16) ^ ((arow & 7) << 4)));
    bf16x8 a7 = *(const bf16x8*)(h2s + ((arow * 512 + 7 * 64 + g * 16) ^ ((arow & 7) << 4)));

    char* tw = smem + (mt * 16 + g * 4) * SLOT;
    const int swz = ((mt * 4 + g) & 7) << 4;   // slot-group XOR swizzle

    bf16x8 A0, A1, A2, A3, A4, A5, A6, A7; float Ab;
    bf16x8 B0, B1, B2, B3, B4, B5, B6, B7; float Bb;

#define ISSUE_T(S, TI)                                                              \
  do {                                                                              \
    int t_ = wv + (TI) * 8;                                                         \
    const bf16_t* np_ = W3q + t_ * 4096 + lane * 8;                                 \
    asm volatile("global_load_dwordx4 %0, %1, off" : "=v"(S##0) : "v"(np_));            \
    asm volatile("global_load_dwordx4 %0, %1, off" : "=v"(S##1) : "v"(np_ + 512));      \
    asm volatile("global_load_dwordx4 %0, %1, off" : "=v"(S##2) : "v"(np_ + 1024));     \
    asm volatile("global_load_dwordx4 %0, %1, off" : "=v"(S##3) : "v"(np_ + 1536));     \
    asm volatile("global_load_dwordx4 %0, %1, off" : "=v"(S##4) : "v"(np_ + 2048));     \
    asm volatile("global_load_dwordx4 %0, %1, off" : "=v"(S##5) : "v"(np_ + 2560));     \
    asm volatile("global_load_dwordx4 %0, %1, off" : "=v"(S##6) : "v"(np_ + 3072));     \
    asm volatile("global_load_dwordx4 %0, %1, off" : "=v"(S##7) : "v"(np_ + 3584));     \
    asm volatile("global_load_dword %0, %1, off"   : "=v"(S##b) : "v"(b3p + t_ * 16 + c)); \
  } while (0)

#define WAIT_N(N)                                          \
  do {                                                     \
    asm volatile("s_waitcnt vmcnt(" #N ")" ::: "memory");  \
    __builtin_amdgcn_sched_barrier(0);                     \
  } while (0)

#define COMP_T(S, TI)                                                    \
  do {                                                                   \
    f32x4 acc0 = {S##b, S##b, S##b, S##b};                               \
    f32x4 acc1 = {0.f, 0.f, 0.f, 0.f};                                   \
    acc0 = MFMA16(a0, S##0, acc0); acc1 = MFMA16(a1, S##1, acc1);        \
    acc0 = MFMA16(a2, S##2, acc0); acc1 = MFMA16(a3, S##3, acc1);        \
    acc0 = MFMA16(a4, S##4, acc0); acc1 = MFMA16(a5, S##5, acc1);        \
    acc0 = MFMA16(a6, S##6, acc0); acc1 = MFMA16(a7, S##7, acc1);        \
    f32x4 accs = acc0 + acc1;                                            \
    int p_ = (wv + (TI) * 8) * 16 + c;                                   \
    _Pragma("unroll")                                                    \
    for (int r_ = 0; r_ < 4; ++r_) {                                     \
      float v_ = fast_tanh(accs[r_]);                                    \
      *(bf16_t*)(tw + r_ * SLOT + ((p_ * 2) ^ swz)) = (bf16_t)v_;        \
    }                                                                    \
  } while (0)

    ISSUE_T(A, 0);
#pragma unroll 1
    for (int pr = 0; pr < 8; ++pr) {
      ISSUE_T(B, 2 * pr + 1);
      WAIT_N(9);
      COMP_T(A, 2 * pr);
      ISSUE_T(A, 2 * pr + 2);
      WAIT_N(9);
      COMP_T(B, 2 * pr + 1);
    }
    ISSUE_T(B, 17);        // <-- R8's missing issue (the correctness bug)
    WAIT_N(9);
    COMP_T(A, 16);
    WAIT_N(0);
    COMP_T(B, 17);

#undef ISSUE_T
#undef WAIT_N
#undef COMP_T
  }
  __syncthreads();

  // ---- copy-out: slot m -> first 4608 B of batch (blk*32+m)'s out region ----
#pragma unroll
  for (int m2 = 0; m2 < 2; ++m2) {
    int m = w * 2 + m2;
    const char* s = smem + m * SLOT;
    int sw = ((m >> 2) & 7) << 4;
    char* dst = (char*)out + (size_t)(blk * 32 + m) * 16384;
#pragma unroll
    for (int i = 0; i < 5; ++i) {
      int off = i * 1024 + lane * 16;
      if (off < USZ) *(f32x4*)(dst + off) = *(const f32x4*)(s + (off ^ sw));
    }
  }
}

// ---------------- kernel 2: Gram, 1 batch per wave, no barriers ----------------
__global__ void __launch_bounds__(256, 4)
hm_gram_kernel(float* __restrict__ out) {
  extern __shared__ char smem[];  // 4 waves x 4096 B y-staging
  const int tid  = threadIdx.x;
  const int w    = tid >> 6;
  const int lane = tid & 63;
  const int g    = lane >> 4;
  const int c    = lane & 15;

  size_t batch = (size_t)blockIdx.x * 4 + w;
  const char* ub = (const char*)out + batch * 16384;  // padded-triangle u
  char* ys = smem + w * 4096;

  bf16x8 f0, f1, f2, f3, f2b, f3b;
#pragma unroll
  for (int ti = 0; ti < 4; ++ti) {
    int j = ti * 16 + c;
    int Q = j >> 3, s = j & 7;
    int ro = 16 * (4 * Q * (Q + 1) + s * (Q + 1));
    bf16x8 fa = *(const bf16x8*)(ub + ro + g * 16);
    if (ti == 0) f0 = zsel(fa, g * 8 <= j);
    if (ti == 1) f1 = zsel(fa, g * 8 <= j);
    if (ti == 2) f2 = fa;
    if (ti == 3) f3 = fa;
    if (ti >= 2) {
      bf16x8 fb = *(const bf16x8*)(ub + ro + 64 + g * 16);
      fb = zsel(fb, 32 + g * 8 <= j);
      if (ti == 2) f2b = fb;
      else         f3b = fb;
    }
  }

  bf16x8 fA[4] = {f0, f1, f2, f3};
  f32x4 acc[4][4];
#pragma unroll
  for (int ti = 0; ti < 4; ++ti)
#pragma unroll
    for (int tj = 0; tj < 4; ++tj) {
      f32x4 z = {0.f, 0.f, 0.f, 0.f};
      acc[ti][tj] = MFMA16(fA[ti], fA[tj], z);
    }
  acc[2][2] = MFMA16(f2b, f2b, acc[2][2]);
  acc[2][3] = MFMA16(f2b, f3b, acc[2][3]);
  acc[3][2] = MFMA16(f3b, f2b, acc[3][2]);
  acc[3][3] = MFMA16(f3b, f3b, acc[3][3]);

  char* yb = (char*)out + batch * 16384;
#pragma unroll
  for (int ti = 0; ti < 4; ++ti) {
#pragma unroll
    for (int tj = 0; tj < 4; ++tj)
#pragma unroll
      for (int r = 0; r < 4; ++r)
        *(float*)(ys + (g * 4 + r) * 256 + (tj * 16 + c) * 4) = acc[ti][tj][r];
#pragma unroll
    for (int ii = 0; ii < 4; ++ii) {
      f32x4 v = *(const f32x4*)(ys + ii * 1024 + lane * 16);
      *(f32x4*)(yb + ti * 4096 + ii * 1024 + lane * 16) = v;
    }
  }
}

extern "C" void kernel_launch(void* const* d_in, const int* in_sizes, int n_in,
                              void* d_out, int out_size, void* d_ws, size_t ws_size,
                              hipStream_t stream) {
  (void)in_sizes; (void)n_in; (void)out_size; (void)ws_size;
  const float* x  = (const float*)d_in[0];
  const float* W1 = (const float*)d_in[1];
  const float* b1 = (const float*)d_in[2];
  const float* W2 = (const float*)d_in[3];
  const float* b2 = (const float*)d_in[4];
  const float* W3 = (const float*)d_in[5];
  const float* b3 = (const float*)d_in[6];
  char* wsb = (char*)d_ws;   // needs 1,352,704 B
  float* out = (float*)d_out;

  prep_kernel<<<1317, 512, 0, stream>>>(W1, W2, W3, b3, wsb);

  hipFuncSetAttribute((const void*)hm_mlp_kernel,
                      hipFuncAttributeMaxDynamicSharedMemorySize, 163840);
  hm_mlp_kernel<<<1024, 1024, 163840, stream>>>(x, b1, b2, wsb, out);

  hm_gram_kernel<<<8192, 256, 16384, stream>>>(out);
}

// Round 10
// 213.934 us; speedup vs baseline: 2.0738x; 1.2936x over previous
//
#include <hip/hip_runtime.h>

// HamiltonianMetric: y[b] = u^T u, u = scatter(tanh(MLP(x))).
// R10: FUSED. Stage 4 (Gram) now runs in the same kernel, reading u frags
// directly from the LDS slots stage 3 just wrote (no u round-trip through
// HBM, no second kernel). Slot becomes y-staging after its frags are read.
// Keeps R9's proven stage 3: W3 tile-major 1KB-burst loads + asm vmcnt pipe.

typedef __bf16 bf16_t;
typedef bf16_t bf16x8 __attribute__((ext_vector_type(8)));
typedef float  f32x4  __attribute__((ext_vector_type(4)));

#define MFMA16(a, b, c) __builtin_amdgcn_mfma_f32_16x16x32_bf16((a), (b), (c), 0, 0, 0)

constexpr int SLOT  = 4608;   // bytes per uT slot (XOR-swizzled)
constexpr int H2OFF = 147456; // 32*SLOT; h2s at [147456,163840)

__device__ __forceinline__ float fast_tanh(float x) {
  float cx = fminf(fmaxf(x, -30.0f), 30.0f);
  float t  = __expf(2.0f * cx);
  return (t - 1.0f) * __builtin_amdgcn_rcpf(t + 1.0f);
}

__device__ __forceinline__ bf16x8 zsel(bf16x8 f, bool keep) {
  union { bf16x8 v; unsigned int u[4]; } x;
  x.v = f;
  unsigned m = keep ? 0xFFFFFFFFu : 0u;
#pragma unroll
  for (int p = 0; p < 4; ++p) x.u[p] &= m;
  return x.v;
}

// padded position p -> (j, k): row j has j+1 valid entries, padded to 8-mult
__device__ __forceinline__ void decode_p(int p, int& j, int& k) {
  int cc = p >> 3, e = p & 7;
  int b = 0;
  while (b < 7 && cc >= 4 * (b + 1) * (b + 2)) ++b;
  int rl  = b + 1;
  int rem = cc - 4 * b * (b + 1);
  j = 8 * b + rem / rl;
  k = (rem % rl) * 8 + e;
}

// ws: [0,16384) W1t[256n][64k] | [16384,81920) W2t[256n][256k] |
//     [81920,671744) W3q tile-major: [144 t][8 kk][64 lane][8 e]
//     byte 1343488: b3p[2304] f32 (permuted triangle bias, 0 in padding)
__global__ void prep_kernel(const float* __restrict__ W1, const float* __restrict__ W2,
                            const float* __restrict__ W3, const float* __restrict__ b3,
                            char* __restrict__ wsb) {
  int tid = blockIdx.x * 512 + threadIdx.x;
  bf16_t* ws = (bf16_t*)wsb;
  if (tid < 16384) {
    int n = tid >> 6, k = tid & 63;
    ws[tid] = (bf16_t)W1[k * 256 + n];
  } else if (tid < 81920) {
    int m = tid - 16384;
    int n = m >> 8, k = m & 255;
    ws[tid] = (bf16_t)W2[k * 256 + n];
  } else if (tid < 671744) {
    int m = tid - 81920;
    int t  = m >> 12;
    int r  = m & 4095;
    int kk = r >> 9;
    int g  = (r >> 7) & 3;
    int c  = (r >> 3) & 15;
    int e  = r & 7;
    int p  = t * 16 + c;          // triangle position
    int k  = kk * 32 + g * 8 + e; // H-dim column
    int j, kd;
    decode_p(p, j, kd);
    float v = 0.f;
    if (kd <= j) {
      int n_ref = (kd == j) ? j : (64 + kd * 63 - (kd * (kd - 1)) / 2 + j - kd - 1);
      v = W3[k * 2080 + n_ref];
    }
    ws[tid] = (bf16_t)v;
  } else if (tid < 674048) {
    int p = tid - 671744;
    int j, kd;
    decode_p(p, j, kd);
    float v = 0.f;
    if (kd <= j) {
      int n_ref = (kd == j) ? j : (64 + kd * 63 - (kd * (kd - 1)) / 2 + j - kd - 1);
      v = b3[n_ref];
    }
    ((float*)(wsb + 1343488))[p] = v;
  }
}

// ---------------- fused kernel: 32 batches/block, 16 waves ----------------
__global__ void __launch_bounds__(1024, 4)
hm_kernel(const float* __restrict__ x, const float* __restrict__ b1,
          const float* __restrict__ b2, const char* __restrict__ wsb,
          float* __restrict__ out) {
  extern __shared__ char smem[];  // 163840 B
  const int tid  = threadIdx.x;
  const int w    = tid >> 6;    // wave 0..15
  const int wv   = w & 7;       // n-tile lane
  const int mt   = w >> 3;      // m-half (0/1)
  const int lane = tid & 63;
  const int g    = lane >> 4;
  const int c    = lane & 15;
  const int blk  = blockIdx.x;

  const bf16_t* W1t = (const bf16_t*)wsb;
  const bf16_t* W2t = W1t + 16384;
  const bf16_t* W3q = W1t + 81920;
  const float*  b3p = (const float*)(wsb + 1343488);

  char* xs  = smem;          // [32][64]  bf16, swz (stage 1 only)
  char* h1s = smem + 8192;   // [32][256] bf16, swz (stages 1-2)
  char* h2s = smem + H2OFF;  // [32][256] bf16, swz (stages 2-3)

  // ---- load x: 32 rows x 64 f32 -> bf16 LDS ----
  if (tid < 512) {
    f32x4 v = *(const f32x4*)(x + (size_t)blk * 2048 + tid * 4);
    int row = tid >> 4, col = (tid & 15) * 4;
    union { bf16_t b[4]; unsigned long long u; } pk;
    pk.b[0] = (bf16_t)v[0]; pk.b[1] = (bf16_t)v[1];
    pk.b[2] = (bf16_t)v[2]; pk.b[3] = (bf16_t)v[3];
    *(unsigned long long*)(xs + ((row * 128 + col * 2) ^ ((row & 7) << 4))) = pk.u;
  }
  __syncthreads();

  // ---- stage 1: h1 = tanh(x @ W1 + b1) ----
  {
    int arow = mt * 16 + c;
    bf16x8 a0 = *(const bf16x8*)(xs + ((arow * 128 + g * 16) ^ ((arow & 7) << 4)));
    bf16x8 a1 = *(const bf16x8*)(xs + ((arow * 128 + 64 + g * 16) ^ ((arow & 7) << 4)));
#pragma unroll
    for (int ni = 0; ni < 2; ++ni) {
      int n = (wv * 2 + ni) * 16 + c;
      bf16x8 bw0 = *(const bf16x8*)(W1t + n * 64 + g * 8);
      bf16x8 bw1 = *(const bf16x8*)(W1t + n * 64 + 32 + g * 8);
      f32x4 acc = {0.f, 0.f, 0.f, 0.f};
      acc = MFMA16(a0, bw0, acc);
      acc = MFMA16(a1, bw1, acc);
      float bias = b1[n];
#pragma unroll
      for (int r = 0; r < 4; ++r) {
        int row = mt * 16 + g * 4 + r;
        float v = fast_tanh(acc[r] + bias);
        *(bf16_t*)(h1s + ((row * 512 + n * 2) ^ ((row & 7) << 4))) = (bf16_t)v;
      }
    }
  }
  __syncthreads();

  // ---- stage 2: h2 = tanh(h1 @ W2 + b2) ----
#pragma unroll
  for (int ni = 0; ni < 2; ++ni) {
    int n = (wv * 2 + ni) * 16 + c;
    int arow = mt * 16 + c;
    f32x4 acc0 = {0.f, 0.f, 0.f, 0.f}, acc1 = {0.f, 0.f, 0.f, 0.f};
#pragma unroll
    for (int kk = 0; kk < 8; kk += 2) {
      bf16x8 a0 = *(const bf16x8*)(h1s + ((arow * 512 + kk * 64 + g * 16) ^ ((arow & 7) << 4)));
      bf16x8 a1 = *(const bf16x8*)(h1s + ((arow * 512 + (kk + 1) * 64 + g * 16) ^ ((arow & 7) << 4)));
      bf16x8 bw0 = *(const bf16x8*)(W2t + n * 256 + kk * 32 + g * 8);
      bf16x8 bw1 = *(const bf16x8*)(W2t + n * 256 + (kk + 1) * 32 + g * 8);
      acc0 = MFMA16(a0, bw0, acc0);
      acc1 = MFMA16(a1, bw1, acc1);
    }
    f32x4 acc = acc0 + acc1;
    float bias = b2[n];
#pragma unroll
    for (int r = 0; r < 4; ++r) {
      int row = mt * 16 + g * 4 + r;
      float v = fast_tanh(acc[r] + bias);
      *(bf16_t*)(h2s + ((row * 512 + n * 2) ^ ((row & 7) << 4))) = (bf16_t)v;
    }
  }
  __syncthreads();

  // ---- stage 3: t = tanh(h2 @ W3 + b3) -> 32 uT slots (XOR-swizzled) ----
  {
    int arow = mt * 16 + c;
    bf16x8 a0 = *(const bf16x8*)(h2s + ((arow * 512 + 0 * 64 + g * 16) ^ ((arow & 7) << 4)));
    bf16x8 a1 = *(const bf16x8*)(h2s + ((arow * 512 + 1 * 64 + g * 16) ^ ((arow & 7) << 4)));
    bf16x8 a2 = *(const bf16x8*)(h2s + ((arow * 512 + 2 * 64 + g * 16) ^ ((arow & 7) << 4)));
    bf16x8 a3 = *(const bf16x8*)(h2s + ((arow * 512 + 3 * 64 + g * 16) ^ ((arow & 7) << 4)));
    bf16x8 a4 = *(const bf16x8*)(h2s + ((arow * 512 + 4 * 64 + g * 16) ^ ((arow & 7) << 4)));
    bf16x8 a5 = *(const bf16x8*)(h2s + ((arow * 512 + 5 * 64 + g * 16) ^ ((arow & 7) << 4)));
    bf16x8 a6 = *(const bf16x8*)(h2s + ((arow * 512 + 6 * 64 + g * 16) ^ ((arow & 7) << 4)));
    bf16x8 a7 = *(const bf16x8*)(h2s + ((arow * 512 + 7 * 64 + g * 16) ^ ((arow & 7) << 4)));

    char* tw = smem + (mt * 16 + g * 4) * SLOT;
    const int swz = ((mt * 4 + g) & 7) << 4;   // slot-group XOR swizzle

    bf16x8 A0, A1, A2, A3, A4, A5, A6, A7; float Ab;
    bf16x8 B0, B1, B2, B3, B4, B5, B6, B7; float Bb;

#define ISSUE_T(S, TI)                                                              \
  do {                                                                              \
    int t_ = wv + (TI) * 8;                                                         \
    const bf16_t* np_ = W3q + t_ * 4096 + lane * 8;                                 \
    asm volatile("global_load_dwordx4 %0, %1, off" : "=v"(S##0) : "v"(np_));            \
    asm volatile("global_load_dwordx4 %0, %1, off" : "=v"(S##1) : "v"(np_ + 512));      \
    asm volatile("global_load_dwordx4 %0, %1, off" : "=v"(S##2) : "v"(np_ + 1024));     \
    asm volatile("global_load_dwordx4 %0, %1, off" : "=v"(S##3) : "v"(np_ + 1536));     \
    asm volatile("global_load_dwordx4 %0, %1, off" : "=v"(S##4) : "v"(np_ + 2048));     \
    asm volatile("global_load_dwordx4 %0, %1, off" : "=v"(S##5) : "v"(np_ + 2560));     \
    asm volatile("global_load_dwordx4 %0, %1, off" : "=v"(S##6) : "v"(np_ + 3072));     \
    asm volatile("global_load_dwordx4 %0, %1, off" : "=v"(S##7) : "v"(np_ + 3584));     \
    asm volatile("global_load_dword %0, %1, off"   : "=v"(S##b) : "v"(b3p + t_ * 16 + c)); \
  } while (0)

#define WAIT_N(N)                                          \
  do {                                                     \
    asm volatile("s_waitcnt vmcnt(" #N ")" ::: "memory");  \
    __builtin_amdgcn_sched_barrier(0);                     \
  } while (0)

#define COMP_T(S, TI)                                                    \
  do {                                                                   \
    f32x4 acc0 = {S##b, S##b, S##b, S##b};                               \
    f32x4 acc1 = {0.f, 0.f, 0.f, 0.f};                                   \
    acc0 = MFMA16(a0, S##0, acc0); acc1 = MFMA16(a1, S##1, acc1);        \
    acc0 = MFMA16(a2, S##2, acc0); acc1 = MFMA16(a3, S##3, acc1);        \
    acc0 = MFMA16(a4, S##4, acc0); acc1 = MFMA16(a5, S##5, acc1);        \
    acc0 = MFMA16(a6, S##6, acc0); acc1 = MFMA16(a7, S##7, acc1);        \
    f32x4 accs = acc0 + acc1;                                            \
    int p_ = (wv + (TI) * 8) * 16 + c;                                   \
    _Pragma("unroll")                                                    \
    for (int r_ = 0; r_ < 4; ++r_) {                                     \
      float v_ = fast_tanh(accs[r_]);                                    \
      *(bf16_t*)(tw + r_ * SLOT + ((p_ * 2) ^ swz)) = (bf16_t)v_;        \
    }                                                                    \
  } while (0)

    ISSUE_T(A, 0);
#pragma unroll 1
    for (int pr = 0; pr < 8; ++pr) {
      ISSUE_T(B, 2 * pr + 1);
      WAIT_N(9);
      COMP_T(A, 2 * pr);
      ISSUE_T(A, 2 * pr + 2);
      WAIT_N(9);
      COMP_T(B, 2 * pr + 1);
    }
    ISSUE_T(B, 17);
    WAIT_N(9);
    COMP_T(A, 16);
    WAIT_N(0);
    COMP_T(B, 17);

#undef ISSUE_T
#undef WAIT_N
#undef COMP_T
  }
  __syncthreads();

  // ---- stage 4 (fused Gram): wave w -> batches 2w, 2w+1, straight from LDS ----
#pragma unroll
  for (int bi = 0; bi < 2; ++bi) {
    int m = w * 2 + bi;
    char* slot = smem + m * SLOT;
    const int sw = ((m >> 2) & 7) << 4;

    bf16x8 f0, f1, f2, f3, f2b, f3b;
#pragma unroll
    for (int ti = 0; ti < 4; ++ti) {
      int j = ti * 16 + c;
      int Q = j >> 3, s = j & 7;
      int ro = 16 * (4 * Q * (Q + 1) + s * (Q + 1));
      bf16x8 fa = *(const bf16x8*)(slot + ((ro + g * 16) ^ sw));
      if (ti == 0) f0 = zsel(fa, g * 8 <= j);
      if (ti == 1) f1 = zsel(fa, g * 8 <= j);
      if (ti == 2) f2 = fa;
      if (ti == 3) f3 = fa;
      if (ti >= 2) {
        bf16x8 fb = *(const bf16x8*)(slot + ((ro + 64 + g * 16) ^ sw));
        fb = zsel(fb, 32 + g * 8 <= j);
        if (ti == 2) f2b = fb;
        else         f3b = fb;
      }
    }

    bf16x8 fA[4] = {f0, f1, f2, f3};
    f32x4 acc[4][4];
#pragma unroll
    for (int ti = 0; ti < 4; ++ti)
#pragma unroll
      for (int tj = 0; tj < 4; ++tj) {
        f32x4 z = {0.f, 0.f, 0.f, 0.f};
        acc[ti][tj] = MFMA16(fA[ti], fA[tj], z);
      }
    acc[2][2] = MFMA16(f2b, f2b, acc[2][2]);
    acc[2][3] = MFMA16(f2b, f3b, acc[2][3]);
    acc[3][2] = MFMA16(f3b, f2b, acc[3][2]);
    acc[3][3] = MFMA16(f3b, f3b, acc[3][3]);

    // slot is dead now -> reuse as 4KB y-staging; 1KB-contiguous stores
    float* yb = out + (size_t)(blk * 32 + m) * 4096;
#pragma unroll
    for (int ti = 0; ti < 4; ++ti) {
#pragma unroll
      for (int tj = 0; tj < 4; ++tj)
#pragma unroll
        for (int r = 0; r < 4; ++r)
          *(float*)(slot + (g * 4 + r) * 256 + (tj * 16 + c) * 4) = acc[ti][tj][r];
#pragma unroll
      for (int ii = 0; ii < 4; ++ii) {
        f32x4 v = *(const f32x4*)(slot + ii * 1024 + lane * 16);
        *(f32x4*)(yb + ti * 1024 + ii * 256 + lane * 4) = v;
      }
    }
  }
}

extern "C" void kernel_launch(void* const* d_in, const int* in_sizes, int n_in,
                              void* d_out, int out_size, void* d_ws, size_t ws_size,
                              hipStream_t stream) {
  (void)in_sizes; (void)n_in; (void)out_size; (void)ws_size;
  const float* x  = (const float*)d_in[0];
  const float* W1 = (const float*)d_in[1];
  const float* b1 = (const float*)d_in[2];
  const float* W2 = (const float*)d_in[3];
  const float* b2 = (const float*)d_in[4];
  const float* W3 = (const float*)d_in[5];
  const float* b3 = (const float*)d_in[6];
  char* wsb = (char*)d_ws;   // needs 1,352,704 B
  float* out = (float*)d_out;

  prep_kernel<<<1317, 512, 0, stream>>>(W1, W2, W3, b3, wsb);

  hipFuncSetAttribute((const void*)hm_kernel,
                      hipFuncAttributeMaxDynamicSharedMemorySize, 163840);
  hm_kernel<<<1024, 1024, 163840, stream>>>(x, b1, b2, wsb, out);
}

// Round 11
// 184.824 us; speedup vs baseline: 2.4004x; 1.1575x over previous
//
#include <hip/hip_runtime.h>

// HamiltonianMetric: y[b] = u^T u, u = scatter(tanh(MLP(x))).
// R11: dedup W3 across batch halves. 8 waves x 512 thr, 32 batches/block:
// each wave holds A-frags for BOTH halves (rows c and 16+c) and does 16 MFMAs
// per W3 tile against ONE loaded B-tile -> W3 L2 traffic halves (2.36->1.18
// MB/CU/gen). W3q layout, prep, vmcnt pipeline, swizzles, gram unchanged.

typedef __bf16 bf16_t;
typedef bf16_t bf16x8 __attribute__((ext_vector_type(8)));
typedef float  f32x4  __attribute__((ext_vector_type(4)));

#define MFMA16(a, b, c) __builtin_amdgcn_mfma_f32_16x16x32_bf16((a), (b), (c), 0, 0, 0)

constexpr int SLOT  = 4608;   // bytes per uT slot (XOR-swizzled)
constexpr int H2OFF = 147456; // 32*SLOT; h2s at [147456,163840)

__device__ __forceinline__ float fast_tanh(float x) {
  float cx = fminf(fmaxf(x, -30.0f), 30.0f);
  float t  = __expf(2.0f * cx);
  return (t - 1.0f) * __builtin_amdgcn_rcpf(t + 1.0f);
}

__device__ __forceinline__ bf16x8 zsel(bf16x8 f, bool keep) {
  union { bf16x8 v; unsigned int u[4]; } x;
  x.v = f;
  unsigned m = keep ? 0xFFFFFFFFu : 0u;
#pragma unroll
  for (int p = 0; p < 4; ++p) x.u[p] &= m;
  return x.v;
}

// padded position p -> (j, k): row j has j+1 valid entries, padded to 8-mult
__device__ __forceinline__ void decode_p(int p, int& j, int& k) {
  int cc = p >> 3, e = p & 7;
  int b = 0;
  while (b < 7 && cc >= 4 * (b + 1) * (b + 2)) ++b;
  int rl  = b + 1;
  int rem = cc - 4 * b * (b + 1);
  j = 8 * b + rem / rl;
  k = (rem % rl) * 8 + e;
}

// ws: [0,16384) W1t[256n][64k] | [16384,81920) W2t[256n][256k] |
//     [81920,671744) W3q tile-major: [144 t][8 kk][64 lane][8 e]
//     byte 1343488: b3p[2304] f32 (permuted triangle bias, 0 in padding)
__global__ void prep_kernel(const float* __restrict__ W1, const float* __restrict__ W2,
                            const float* __restrict__ W3, const float* __restrict__ b3,
                            char* __restrict__ wsb) {
  int tid = blockIdx.x * 512 + threadIdx.x;
  bf16_t* ws = (bf16_t*)wsb;
  if (tid < 16384) {
    int n = tid >> 6, k = tid & 63;
    ws[tid] = (bf16_t)W1[k * 256 + n];
  } else if (tid < 81920) {
    int m = tid - 16384;
    int n = m >> 8, k = m & 255;
    ws[tid] = (bf16_t)W2[k * 256 + n];
  } else if (tid < 671744) {
    int m = tid - 81920;
    int t  = m >> 12;
    int r  = m & 4095;
    int kk = r >> 9;
    int g  = (r >> 7) & 3;
    int c  = (r >> 3) & 15;
    int e  = r & 7;
    int p  = t * 16 + c;          // triangle position
    int k  = kk * 32 + g * 8 + e; // H-dim column
    int j, kd;
    decode_p(p, j, kd);
    float v = 0.f;
    if (kd <= j) {
      int n_ref = (kd == j) ? j : (64 + kd * 63 - (kd * (kd - 1)) / 2 + j - kd - 1);
      v = W3[k * 2080 + n_ref];
    }
    ws[tid] = (bf16_t)v;
  } else if (tid < 674048) {
    int p = tid - 671744;
    int j, kd;
    decode_p(p, j, kd);
    float v = 0.f;
    if (kd <= j) {
      int n_ref = (kd == j) ? j : (64 + kd * 63 - (kd * (kd - 1)) / 2 + j - kd - 1);
      v = b3[n_ref];
    }
    ((float*)(wsb + 1343488))[p] = v;
  }
}

// ---------------- fused kernel: 32 batches/block, 8 waves ----------------
__global__ void __launch_bounds__(512, 2)
hm_kernel(const float* __restrict__ x, const float* __restrict__ b1,
          const float* __restrict__ b2, const char* __restrict__ wsb,
          float* __restrict__ out) {
  extern __shared__ char smem[];  // 163840 B
  const int tid  = threadIdx.x;
  const int w    = tid >> 6;    // wave 0..7
  const int lane = tid & 63;
  const int g    = lane >> 4;
  const int c    = lane & 15;
  const int blk  = blockIdx.x;

  const bf16_t* W1t = (const bf16_t*)wsb;
  const bf16_t* W2t = W1t + 16384;
  const bf16_t* W3q = W1t + 81920;
  const float*  b3p = (const float*)(wsb + 1343488);

  char* xs  = smem;          // [32][64]  bf16, swz (stage 1 only)
  char* h1s = smem + 8192;   // [32][256] bf16, swz (stages 1-2)
  char* h2s = smem + H2OFF;  // [32][256] bf16, swz (stages 2-3)

  // ---- load x: 32 rows x 64 f32 -> bf16 LDS (512 thr x 4 floats) ----
  {
    f32x4 v = *(const f32x4*)(x + (size_t)blk * 2048 + tid * 4);
    int row = tid >> 4, col = (tid & 15) * 4;
    union { bf16_t b[4]; unsigned long long u; } pk;
    pk.b[0] = (bf16_t)v[0]; pk.b[1] = (bf16_t)v[1];
    pk.b[2] = (bf16_t)v[2]; pk.b[3] = (bf16_t)v[3];
    *(unsigned long long*)(xs + ((row * 128 + col * 2) ^ ((row & 7) << 4))) = pk.u;
  }
  __syncthreads();

  // ---- stage 1: h1 = tanh(x @ W1 + b1); wave covers both mt halves ----
#pragma unroll
  for (int mt = 0; mt < 2; ++mt) {
    int arow = mt * 16 + c;
    bf16x8 a0 = *(const bf16x8*)(xs + ((arow * 128 + g * 16) ^ ((arow & 7) << 4)));
    bf16x8 a1 = *(const bf16x8*)(xs + ((arow * 128 + 64 + g * 16) ^ ((arow & 7) << 4)));
#pragma unroll
    for (int ni = 0; ni < 2; ++ni) {
      int n = (w * 2 + ni) * 16 + c;
      bf16x8 bw0 = *(const bf16x8*)(W1t + n * 64 + g * 8);
      bf16x8 bw1 = *(const bf16x8*)(W1t + n * 64 + 32 + g * 8);
      f32x4 acc = {0.f, 0.f, 0.f, 0.f};
      acc = MFMA16(a0, bw0, acc);
      acc = MFMA16(a1, bw1, acc);
      float bias = b1[n];
#pragma unroll
      for (int r = 0; r < 4; ++r) {
        int row = mt * 16 + g * 4 + r;
        float v = fast_tanh(acc[r] + bias);
        *(bf16_t*)(h1s + ((row * 512 + n * 2) ^ ((row & 7) << 4))) = (bf16_t)v;
      }
    }
  }
  __syncthreads();

  // ---- stage 2: h2 = tanh(h1 @ W2 + b2); both halves per wave ----
#pragma unroll
  for (int mt = 0; mt < 2; ++mt) {
    int arow = mt * 16 + c;
#pragma unroll
    for (int ni = 0; ni < 2; ++ni) {
      int n = (w * 2 + ni) * 16 + c;
      f32x4 acc0 = {0.f, 0.f, 0.f, 0.f}, acc1 = {0.f, 0.f, 0.f, 0.f};
#pragma unroll
      for (int kk = 0; kk < 8; kk += 2) {
        bf16x8 a0 = *(const bf16x8*)(h1s + ((arow * 512 + kk * 64 + g * 16) ^ ((arow & 7) << 4)));
        bf16x8 a1 = *(const bf16x8*)(h1s + ((arow * 512 + (kk + 1) * 64 + g * 16) ^ ((arow & 7) << 4)));
        bf16x8 bw0 = *(const bf16x8*)(W2t + n * 256 + kk * 32 + g * 8);
        bf16x8 bw1 = *(const bf16x8*)(W2t + n * 256 + (kk + 1) * 32 + g * 8);
        acc0 = MFMA16(a0, bw0, acc0);
        acc1 = MFMA16(a1, bw1, acc1);
      }
      f32x4 acc = acc0 + acc1;
      float bias = b2[n];
#pragma unroll
      for (int r = 0; r < 4; ++r) {
        int row = mt * 16 + g * 4 + r;
        float v = fast_tanh(acc[r] + bias);
        *(bf16_t*)(h2s + ((row * 512 + n * 2) ^ ((row & 7) << 4))) = (bf16_t)v;
      }
    }
  }
  __syncthreads();

  // ---- stage 3: t = tanh(h2 @ W3 + b3); ONE B-tile load serves BOTH halves ----
  {
    int arowL = c, arowH = 16 + c;
    bf16x8 aL0 = *(const bf16x8*)(h2s + ((arowL * 512 + 0 * 64 + g * 16) ^ ((arowL & 7) << 4)));
    bf16x8 aL1 = *(const bf16x8*)(h2s + ((arowL * 512 + 1 * 64 + g * 16) ^ ((arowL & 7) << 4)));
    bf16x8 aL2 = *(const bf16x8*)(h2s + ((arowL * 512 + 2 * 64 + g * 16) ^ ((arowL & 7) << 4)));
    bf16x8 aL3 = *(const bf16x8*)(h2s + ((arowL * 512 + 3 * 64 + g * 16) ^ ((arowL & 7) << 4)));
    bf16x8 aL4 = *(const bf16x8*)(h2s + ((arowL * 512 + 4 * 64 + g * 16) ^ ((arowL & 7) << 4)));
    bf16x8 aL5 = *(const bf16x8*)(h2s + ((arowL * 512 + 5 * 64 + g * 16) ^ ((arowL & 7) << 4)));
    bf16x8 aL6 = *(const bf16x8*)(h2s + ((arowL * 512 + 6 * 64 + g * 16) ^ ((arowL & 7) << 4)));
    bf16x8 aL7 = *(const bf16x8*)(h2s + ((arowL * 512 + 7 * 64 + g * 16) ^ ((arowL & 7) << 4)));
    bf16x8 aH0 = *(const bf16x8*)(h2s + ((arowH * 512 + 0 * 64 + g * 16) ^ ((arowH & 7) << 4)));
    bf16x8 aH1 = *(const bf16x8*)(h2s + ((arowH * 512 + 1 * 64 + g * 16) ^ ((arowH & 7) << 4)));
    bf16x8 aH2 = *(const bf16x8*)(h2s + ((arowH * 512 + 2 * 64 + g * 16) ^ ((arowH & 7) << 4)));
    bf16x8 aH3 = *(const bf16x8*)(h2s + ((arowH * 512 + 3 * 64 + g * 16) ^ ((arowH & 7) << 4)));
    bf16x8 aH4 = *(const bf16x8*)(h2s + ((arowH * 512 + 4 * 64 + g * 16) ^ ((arowH & 7) << 4)));
    bf16x8 aH5 = *(const bf16x8*)(h2s + ((arowH * 512 + 5 * 64 + g * 16) ^ ((arowH & 7) << 4)));
    bf16x8 aH6 = *(const bf16x8*)(h2s + ((arowH * 512 + 6 * 64 + g * 16) ^ ((arowH & 7) << 4)));
    bf16x8 aH7 = *(const bf16x8*)(h2s + ((arowH * 512 + 7 * 64 + g * 16) ^ ((arowH & 7) << 4)));

    char* twL = smem + (g * 4) * SLOT;          // slots g*4+r       (mt=0)
    char* twH = smem + (16 + g * 4) * SLOT;     // slots 16+g*4+r    (mt=1)
    const int swzL = (g & 7) << 4;              // ((0*4+g)&7)<<4
    const int swzH = ((4 + g) & 7) << 4;        // ((1*4+g)&7)<<4

    bf16x8 A0, A1, A2, A3, A4, A5, A6, A7; float Ab;
    bf16x8 B0, B1, B2, B3, B4, B5, B6, B7; float Bb;

#define ISSUE_T(S, TI)                                                              \
  do {                                                                              \
    int t_ = w + (TI) * 8;                                                          \
    const bf16_t* np_ = W3q + t_ * 4096 + lane * 8;                                 \
    asm volatile("global_load_dwordx4 %0, %1, off" : "=v"(S##0) : "v"(np_));            \
    asm volatile("global_load_dwordx4 %0, %1, off" : "=v"(S##1) : "v"(np_ + 512));      \
    asm volatile("global_load_dwordx4 %0, %1, off" : "=v"(S##2) : "v"(np_ + 1024));     \
    asm volatile("global_load_dwordx4 %0, %1, off" : "=v"(S##3) : "v"(np_ + 1536));     \
    asm volatile("global_load_dwordx4 %0, %1, off" : "=v"(S##4) : "v"(np_ + 2048));     \
    asm volatile("global_load_dwordx4 %0, %1, off" : "=v"(S##5) : "v"(np_ + 2560));     \
    asm volatile("global_load_dwordx4 %0, %1, off" : "=v"(S##6) : "v"(np_ + 3072));     \
    asm volatile("global_load_dwordx4 %0, %1, off" : "=v"(S##7) : "v"(np_ + 3584));     \
    asm volatile("global_load_dword %0, %1, off"   : "=v"(S##b) : "v"(b3p + t_ * 16 + c)); \
  } while (0)

#define WAIT_N(N)                                          \
  do {                                                     \
    asm volatile("s_waitcnt vmcnt(" #N ")" ::: "memory");  \
    __builtin_amdgcn_sched_barrier(0);                     \
  } while (0)

#define COMP_T(S, TI)                                                      \
  do {                                                                     \
    f32x4 al0 = {S##b, S##b, S##b, S##b}, al1 = {0.f, 0.f, 0.f, 0.f};      \
    f32x4 ah0 = {S##b, S##b, S##b, S##b}, ah1 = {0.f, 0.f, 0.f, 0.f};      \
    al0 = MFMA16(aL0, S##0, al0); al1 = MFMA16(aL1, S##1, al1);            \
    ah0 = MFMA16(aH0, S##0, ah0); ah1 = MFMA16(aH1, S##1, ah1);            \
    al0 = MFMA16(aL2, S##2, al0); al1 = MFMA16(aL3, S##3, al1);            \
    ah0 = MFMA16(aH2, S##2, ah0); ah1 = MFMA16(aH3, S##3, ah1);            \
    al0 = MFMA16(aL4, S##4, al0); al1 = MFMA16(aL5, S##5, al1);            \
    ah0 = MFMA16(aH4, S##4, ah0); ah1 = MFMA16(aH5, S##5, ah1);            \
    al0 = MFMA16(aL6, S##6, al0); al1 = MFMA16(aL7, S##7, al1);            \
    ah0 = MFMA16(aH6, S##6, ah0); ah1 = MFMA16(aH7, S##7, ah1);            \
    f32x4 asL = al0 + al1;                                                 \
    f32x4 asH = ah0 + ah1;                                                 \
    int p_ = (w + (TI) * 8) * 16 + c;                                      \
    _Pragma("unroll")                                                      \
    for (int r_ = 0; r_ < 4; ++r_) {                                       \
      float vL = fast_tanh(asL[r_]);                                       \
      *(bf16_t*)(twL + r_ * SLOT + ((p_ * 2) ^ swzL)) = (bf16_t)vL;        \
      float vH = fast_tanh(asH[r_]);                                       \
      *(bf16_t*)(twH + r_ * SLOT + ((p_ * 2) ^ swzH)) = (bf16_t)vH;        \
    }                                                                      \
  } while (0)

    ISSUE_T(A, 0);
#pragma unroll 1
    for (int pr = 0; pr < 8; ++pr) {
      ISSUE_T(B, 2 * pr + 1);
      WAIT_N(9);
      COMP_T(A, 2 * pr);
      ISSUE_T(A, 2 * pr + 2);
      WAIT_N(9);
      COMP_T(B, 2 * pr + 1);
    }
    ISSUE_T(B, 17);
    WAIT_N(9);
    COMP_T(A, 16);
    WAIT_N(0);
    COMP_T(B, 17);

#undef ISSUE_T
#undef WAIT_N
#undef COMP_T
  }
  __syncthreads();

  // ---- stage 4 (fused Gram): wave w -> batches 4w..4w+3, from LDS ----
#pragma unroll
  for (int bi = 0; bi < 4; ++bi) {
    int m = w * 4 + bi;
    char* slot = smem + m * SLOT;
    const int sw = ((m >> 2) & 7) << 4;

    bf16x8 f0, f1, f2, f3, f2b, f3b;
#pragma unroll
    for (int ti = 0; ti < 4; ++ti) {
      int j = ti * 16 + c;
      int Q = j >> 3, s = j & 7;
      int ro = 16 * (4 * Q * (Q + 1) + s * (Q + 1));
      bf16x8 fa = *(const bf16x8*)(slot + ((ro + g * 16) ^ sw));
      if (ti == 0) f0 = zsel(fa, g * 8 <= j);
      if (ti == 1) f1 = zsel(fa, g * 8 <= j);
      if (ti == 2) f2 = fa;
      if (ti == 3) f3 = fa;
      if (ti >= 2) {
        bf16x8 fb = *(const bf16x8*)(slot + ((ro + 64 + g * 16) ^ sw));
        fb = zsel(fb, 32 + g * 8 <= j);
        if (ti == 2) f2b = fb;
        else         f3b = fb;
      }
    }

    bf16x8 fA[4] = {f0, f1, f2, f3};
    f32x4 acc[4][4];
#pragma unroll
    for (int ti = 0; ti < 4; ++ti)
#pragma unroll
      for (int tj = 0; tj < 4; ++tj) {
        f32x4 z = {0.f, 0.f, 0.f, 0.f};
        acc[ti][tj] = MFMA16(fA[ti], fA[tj], z);
      }
    acc[2][2] = MFMA16(f2b, f2b, acc[2][2]);
    acc[2][3] = MFMA16(f2b, f3b, acc[2][3]);
    acc[3][2] = MFMA16(f3b, f2b, acc[3][2]);
    acc[3][3] = MFMA16(f3b, f3b, acc[3][3]);

    // slot is dead now -> reuse as 4KB y-staging; 1KB-contiguous stores
    float* yb = out + (size_t)(blk * 32 + m) * 4096;
#pragma unroll
    for (int ti = 0; ti < 4; ++ti) {
#pragma unroll
      for (int tj = 0; tj < 4; ++tj)
#pragma unroll
        for (int r = 0; r < 4; ++r)
          *(float*)(slot + (g * 4 + r) * 256 + (tj * 16 + c) * 4) = acc[ti][tj][r];
#pragma unroll
      for (int ii = 0; ii < 4; ++ii) {
        f32x4 v = *(const f32x4*)(slot + ii * 1024 + lane * 16);
        *(f32x4*)(yb + ti * 1024 + ii * 256 + lane * 4) = v;
      }
    }
  }
}

extern "C" void kernel_launch(void* const* d_in, const int* in_sizes, int n_in,
                              void* d_out, int out_size, void* d_ws, size_t ws_size,
                              hipStream_t stream) {
  (void)in_sizes; (void)n_in; (void)out_size; (void)ws_size;
  const float* x  = (const float*)d_in[0];
  const float* W1 = (const float*)d_in[1];
  const float* b1 = (const float*)d_in[2];
  const float* W2 = (const float*)d_in[3];
  const float* b2 = (const float*)d_in[4];
  const float* W3 = (const float*)d_in[5];
  const float* b3 = (const float*)d_in[6];
  char* wsb = (char*)d_ws;   // needs 1,352,704 B
  float* out = (float*)d_out;

  prep_kernel<<<1317, 512, 0, stream>>>(W1, W2, W3, b3, wsb);

  hipFuncSetAttribute((const void*)hm_kernel,
                      hipFuncAttributeMaxDynamicSharedMemorySize, 163840);
  hm_kernel<<<1024, 512, 163840, stream>>>(x, b1, b2, wsb, out);
}